// Round 1
// baseline (1560.109 us; speedup 1.0000x reference)
//
#include <hip/hip_runtime.h>
#include <hip/hip_bf16.h>
#include <cstddef>
#include <cstdint>

#define NA 50000
#define NB 10000
#define D_IN 32
#define D_OUT 64
#define EA2A 800000
#define EA2B 400000
#define EB2A 400000

// ---------------- wave helpers ----------------
__device__ __forceinline__ float wredmax(float v) {
#pragma unroll
    for (int off = 32; off; off >>= 1) v = fmaxf(v, __shfl_xor(v, off, 64));
    return v;
}
__device__ __forceinline__ float wredsum(float v) {
#pragma unroll
    for (int off = 32; off; off >>= 1) v += __shfl_xor(v, off, 64);
    return v;
}

// ---------------- xs = H @ W  (N x 64) @ (64 x 64), fused al_s = xs @ a_s ----
__global__ void gemm64_kernel(const float* __restrict__ H, const float* __restrict__ W,
                              const float* __restrict__ As, float* __restrict__ XS,
                              float* __restrict__ ALS, int N)
{
    __shared__ float Wsh[64 * 64];
    int t = threadIdx.x;
    for (int i = t; i < 64 * 64; i += blockDim.x) Wsh[i] = W[i];
    __syncthreads();
    int lane = t & 63;
    int wid = t >> 6;
    int wpb = blockDim.x >> 6;
    float asd = As[lane];
    for (int row = blockIdx.x * wpb + wid; row < N; row += gridDim.x * wpb) {
        float h = H[(size_t)row * 64 + lane];
        float acc = 0.f;
#pragma unroll
        for (int k = 0; k < 64; ++k) {
            acc = fmaf(__shfl(h, k, 64), Wsh[k * 64 + lane], acc);
        }
        XS[(size_t)row * 64 + lane] = acc;
        float v = acc * asd;
#pragma unroll
        for (int off = 32; off; off >>= 1) v += __shfl_xor(v, off, 64);
        if (lane == 0) ALS[row] = v;
    }
}

// ---------------- al_d = Hd @ (Wd @ Ad) ----------------
__global__ void ald_kernel(const float* __restrict__ Hd, const float* __restrict__ Wd,
                           const float* __restrict__ Ad, float* __restrict__ ALD, int N)
{
    __shared__ float vd[64];
    int t = threadIdx.x;
    if (t < 64) {
        float s = 0.f;
#pragma unroll
        for (int d = 0; d < 64; ++d) s += Wd[t * 64 + d] * Ad[d];
        vd[t] = s;
    }
    __syncthreads();
    int lane = t & 63, wid = t >> 6, wpb = blockDim.x >> 6;
    float vk = vd[lane];
    for (int row = blockIdx.x * wpb + wid; row < N; row += gridDim.x * wpb) {
        float v = Hd[(size_t)row * 64 + lane] * vk;
#pragma unroll
        for (int off = 32; off; off >>= 1) v += __shfl_xor(v, off, 64);
        if (lane == 0) ALD[row] = v;
    }
}

// ---------------- CSR build ----------------
__global__ void hist_kernel(const int* __restrict__ dst, int* __restrict__ cnt, int E)
{
    for (int i = blockIdx.x * blockDim.x + threadIdx.x; i < E; i += gridDim.x * blockDim.x)
        atomicAdd(&cnt[dst[i]], 1);
}

__global__ void scan_partial(const int* __restrict__ cnt, int* __restrict__ bsum, int N)
{
    __shared__ int sd[256];
    int t = threadIdx.x;
    int i = blockIdx.x * 256 + t;
    sd[t] = (i < N) ? cnt[i] : 0;
    __syncthreads();
    for (int off = 128; off; off >>= 1) {
        if (t < off) sd[t] += sd[t + off];
        __syncthreads();
    }
    if (t == 0) bsum[blockIdx.x] = sd[0];
}

__global__ void scan_tops(int* bsum, int nb)
{
    if (threadIdx.x == 0 && blockIdx.x == 0) {
        int run = 0;
        for (int b = 0; b < nb; ++b) { int v = bsum[b]; bsum[b] = run; run += v; }
    }
}

__global__ void scan_final(const int* __restrict__ cnt, const int* __restrict__ bsum,
                           int* __restrict__ rowptr, int N)
{
    __shared__ int sd[256];
    int t = threadIdx.x;
    int i = blockIdx.x * 256 + t;
    int v = (i < N) ? cnt[i] : 0;
    sd[t] = v;
    __syncthreads();
    for (int off = 1; off < 256; off <<= 1) {
        int add = (t >= off) ? sd[t - off] : 0;
        __syncthreads();
        sd[t] += add;
        __syncthreads();
    }
    if (i < N) rowptr[i] = bsum[blockIdx.x] + sd[t] - v;   // exclusive prefix
}

__global__ void csr_fill(const int* __restrict__ esrc, const int* __restrict__ edst,
                         const int* __restrict__ rowptr, int* __restrict__ fpos,
                         int* __restrict__ csrc, int E)
{
    for (int i = blockIdx.x * blockDim.x + threadIdx.x; i < E; i += gridDim.x * blockDim.x) {
        int d = edst[i];
        int p = atomicAdd(&fpos[d], 1);
        csrc[rowptr[d] + p] = esrc[i];
    }
}

// ---------------- per-destination GAT contribution (flash-style online softmax)
__device__ __forceinline__ float gat_contrib(int i, int lane,
        const int* __restrict__ rp, const int* __restrict__ cnt, const int* __restrict__ src,
        const float* __restrict__ als, const float* __restrict__ ald,
        const float* __restrict__ xs)
{
    int beg = rp[i];
    int deg = cnt[i];
    float aldi = ald[i];
    float m = -1e30f, ssum = 0.f, acc = 0.f;
    for (int base = 0; base < deg; base += 64) {
        int j = base + lane;
        int sj = 0;
        float e = -1e30f;
        if (j < deg) {
            sj = src[beg + j];
            float tv = als[sj] + aldi;
            e = (tv > 0.f) ? tv : 0.2f * tv;
        }
        float cm = wredmax(e);
        if (cm > m) {
            float sc = __expf(m - cm);
            acc *= sc;
            ssum *= sc;
            m = cm;
        }
        float p = (j < deg) ? __expf(e - m) : 0.f;
        ssum += wredsum(p);
        int c = deg - base;
        if (c > 64) c = 64;
#pragma unroll 4
        for (int jj = 0; jj < c; ++jj) {
            float pj = __shfl(p, jj, 64);
            int sjj = __shfl(sj, jj, 64);
            acc = fmaf(pj, xs[(size_t)sjj * 64 + lane], acc);
        }
    }
    return acc / (ssum + 1e-16f);
}

// MODE: 0 = z gate (write sigmoid), 1 = r gate (write sigmoid*h), 2 = n gate (write GRU combine)
// TWOET: 1 => two edge types (destination type A), 0 => one (destination type B)
template <int MODE, int TWOET>
__global__ void __launch_bounds__(256) aggregate_kernel(
    const int* __restrict__ rp1, const int* __restrict__ cnt1, const int* __restrict__ src1,
    const float* __restrict__ als1, const float* __restrict__ ald1, const float* __restrict__ xs1,
    const float* __restrict__ gb1,
    const int* __restrict__ rp2, const int* __restrict__ cnt2, const int* __restrict__ src2,
    const float* __restrict__ als2, const float* __restrict__ ald2, const float* __restrict__ xs2,
    const float* __restrict__ gb2,
    const float* __restrict__ X, const float* __restrict__ WX, const float* __restrict__ BX,
    const float* __restrict__ H, const float* __restrict__ Z,
    float* __restrict__ OUT, int N)
{
    int t = threadIdx.x;
    int lane = t & 63, wid = t >> 6, wpb = blockDim.x >> 6;
    float wxc[32];
#pragma unroll
    for (int k = 0; k < 32; ++k) wxc[k] = WX[k * 64 + lane];
    float cb = gb1[lane] + BX[lane];
    if (TWOET) cb += gb2[lane];
    for (int i = blockIdx.x * wpb + wid; i < N; i += gridDim.x * wpb) {
        float xv = (lane < 32) ? X[(size_t)i * 32 + lane] : 0.f;
        float pre = cb;
#pragma unroll
        for (int k = 0; k < 32; ++k) pre = fmaf(__shfl(xv, k, 64), wxc[k], pre);
        pre += gat_contrib(i, lane, rp1, cnt1, src1, als1, ald1, xs1);
        if (TWOET) pre += gat_contrib(i, lane, rp2, cnt2, src2, als2, ald2, xs2);
        size_t o = (size_t)i * 64 + lane;
        if (MODE == 0) {
            OUT[o] = 1.f / (1.f + __expf(-pre));
        } else if (MODE == 1) {
            OUT[o] = (1.f / (1.f + __expf(-pre))) * H[o];
        } else {
            float x2 = pre * 2.f;
            x2 = fminf(fmaxf(x2, -30.f), 30.f);
            float ex = __expf(x2);
            float nv = (ex - 1.f) / (ex + 1.f);
            float zv = Z[o];
            OUT[o] = (1.f - zv) * nv + zv * H[o];
        }
    }
}

// ---------------- host side ----------------
extern "C" void kernel_launch(void* const* d_in, const int* in_sizes, int n_in,
                              void* d_out, int out_size, void* d_ws, size_t ws_size,
                              hipStream_t stream)
{
    (void)in_sizes; (void)n_in; (void)out_size; (void)ws_size;
    const float* x_a = (const float*)d_in[0];
    const float* x_b = (const float*)d_in[1];
    const float* h_a = (const float*)d_in[2];
    const float* h_b = (const float*)d_in[3];
    const float* Wx  = (const float*)d_in[4];
    const float* bx  = (const float*)d_in[5];
    const float* gws = (const float*)d_in[6];
    const float* gwd = (const float*)d_in[7];
    const float* gas = (const float*)d_in[8];
    const float* gad = (const float*)d_in[9];
    const float* gb  = (const float*)d_in[10];
    const int* ea2a_s = (const int*)d_in[11];
    const int* ea2a_d = (const int*)d_in[12];
    const int* ea2b_s = (const int*)d_in[13];
    const int* ea2b_d = (const int*)d_in[14];
    const int* eb2a_s = (const int*)d_in[15];
    const int* eb2a_d = (const int*)d_in[16];
    float* out = (float*)d_out;

    char* w = (char*)d_ws;
    auto alloc = [&](size_t bytes) -> char* {
        char* p = w;
        w += (bytes + 255) & ~(size_t)255;
        return p;
    };
    float* xs0  = (float*)alloc((size_t)NA * 64 * 4);
    float* xs1  = (float*)alloc((size_t)NA * 64 * 4);
    float* xs2  = (float*)alloc((size_t)NB * 64 * 4);
    float* als0 = (float*)alloc((size_t)NA * 4);
    float* als1 = (float*)alloc((size_t)NA * 4);
    float* als2 = (float*)alloc((size_t)NB * 4);
    float* ald0 = (float*)alloc((size_t)NA * 4);
    float* ald1 = (float*)alloc((size_t)NB * 4);
    float* ald2 = (float*)alloc((size_t)NA * 4);
    float* zbuf = (float*)alloc((size_t)(NA + NB) * 64 * 4);
    float* rhbuf= (float*)alloc((size_t)(NA + NB) * 64 * 4);
    // cnt / fpos contiguous for a single memset
    char* zero_begin = w;
    int* cnt0 = (int*)alloc((size_t)NA * 4);
    int* cnt1 = (int*)alloc((size_t)NB * 4);
    int* cnt2 = (int*)alloc((size_t)NA * 4);
    int* fp0  = (int*)alloc((size_t)NA * 4);
    int* fp1  = (int*)alloc((size_t)NB * 4);
    int* fp2  = (int*)alloc((size_t)NA * 4);
    char* zero_end = w;
    int* rp0  = (int*)alloc((size_t)NA * 4);
    int* rp1  = (int*)alloc((size_t)NB * 4);
    int* rp2  = (int*)alloc((size_t)NA * 4);
    int* csr0 = (int*)alloc((size_t)EA2A * 4);
    int* csr1 = (int*)alloc((size_t)EA2B * 4);
    int* csr2 = (int*)alloc((size_t)EB2A * 4);
    int* bsum = (int*)alloc(256 * 4);

    const int nbA = (NA + 255) / 256;
    const int nbB = (NB + 255) / 256;

    // ---- CSR build (edge-structure only; shared across all 3 gates) ----
    hipMemsetAsync(zero_begin, 0, (size_t)(zero_end - zero_begin), stream);
    hist_kernel<<<1024, 256, 0, stream>>>(ea2a_d, cnt0, EA2A);
    hist_kernel<<<1024, 256, 0, stream>>>(ea2b_d, cnt1, EA2B);
    hist_kernel<<<1024, 256, 0, stream>>>(eb2a_d, cnt2, EB2A);

    scan_partial<<<nbA, 256, 0, stream>>>(cnt0, bsum, NA);
    scan_tops<<<1, 64, 0, stream>>>(bsum, nbA);
    scan_final<<<nbA, 256, 0, stream>>>(cnt0, bsum, rp0, NA);

    scan_partial<<<nbB, 256, 0, stream>>>(cnt1, bsum, NB);
    scan_tops<<<1, 64, 0, stream>>>(bsum, nbB);
    scan_final<<<nbB, 256, 0, stream>>>(cnt1, bsum, rp1, NB);

    scan_partial<<<nbA, 256, 0, stream>>>(cnt2, bsum, NA);
    scan_tops<<<1, 64, 0, stream>>>(bsum, nbA);
    scan_final<<<nbA, 256, 0, stream>>>(cnt2, bsum, rp2, NA);

    csr_fill<<<1024, 256, 0, stream>>>(ea2a_s, ea2a_d, rp0, fp0, csr0, EA2A);
    csr_fill<<<1024, 256, 0, stream>>>(ea2b_s, ea2b_d, rp1, fp1, csr1, EA2B);
    csr_fill<<<1024, 256, 0, stream>>>(eb2a_s, eb2a_d, rp2, fp2, csr2, EB2A);

    const int gridA = (NA + 3) / 4;
    const int gridB = (NB + 3) / 4;

    float* rh_a = rhbuf;
    float* rh_b = rhbuf + (size_t)NA * 64;

    // ---- gates z (g=0) and r (g=1): conv input is h ----
    for (int g = 0; g < 2; ++g) {
        gemm64_kernel<<<gridA, 256, 0, stream>>>(h_a, gws + (g * 3 + 0) * 4096, gas + (g * 3 + 0) * 64, xs0, als0, NA);
        gemm64_kernel<<<gridA, 256, 0, stream>>>(h_a, gws + (g * 3 + 1) * 4096, gas + (g * 3 + 1) * 64, xs1, als1, NA);
        gemm64_kernel<<<gridB, 256, 0, stream>>>(h_b, gws + (g * 3 + 2) * 4096, gas + (g * 3 + 2) * 64, xs2, als2, NB);
        ald_kernel<<<gridA, 256, 0, stream>>>(h_a, gwd + (g * 3 + 0) * 4096, gad + (g * 3 + 0) * 64, ald0, NA);
        ald_kernel<<<gridB, 256, 0, stream>>>(h_b, gwd + (g * 3 + 1) * 4096, gad + (g * 3 + 1) * 64, ald1, NB);
        ald_kernel<<<gridA, 256, 0, stream>>>(h_a, gwd + (g * 3 + 2) * 4096, gad + (g * 3 + 2) * 64, ald2, NA);

        float* outA = (g == 0) ? zbuf : rh_a;
        float* outB = (g == 0) ? zbuf + (size_t)NA * 64 : rh_b;
        if (g == 0) {
            aggregate_kernel<0, 1><<<gridA, 256, 0, stream>>>(
                rp0, cnt0, csr0, als0, ald0, xs0, gb + (g * 3 + 0) * 64,
                rp2, cnt2, csr2, als2, ald2, xs2, gb + (g * 3 + 2) * 64,
                x_a, Wx + (g * 2 + 0) * 2048, bx + (g * 2 + 0) * 64,
                h_a, nullptr, outA, NA);
            aggregate_kernel<0, 0><<<gridB, 256, 0, stream>>>(
                rp1, cnt1, csr1, als1, ald1, xs1, gb + (g * 3 + 1) * 64,
                nullptr, nullptr, nullptr, nullptr, nullptr, nullptr, nullptr,
                x_b, Wx + (g * 2 + 1) * 2048, bx + (g * 2 + 1) * 64,
                h_b, nullptr, outB, NB);
        } else {
            aggregate_kernel<1, 1><<<gridA, 256, 0, stream>>>(
                rp0, cnt0, csr0, als0, ald0, xs0, gb + (g * 3 + 0) * 64,
                rp2, cnt2, csr2, als2, ald2, xs2, gb + (g * 3 + 2) * 64,
                x_a, Wx + (g * 2 + 0) * 2048, bx + (g * 2 + 0) * 64,
                h_a, nullptr, outA, NA);
            aggregate_kernel<1, 0><<<gridB, 256, 0, stream>>>(
                rp1, cnt1, csr1, als1, ald1, xs1, gb + (g * 3 + 1) * 64,
                nullptr, nullptr, nullptr, nullptr, nullptr, nullptr, nullptr,
                x_b, Wx + (g * 2 + 1) * 2048, bx + (g * 2 + 1) * 64,
                h_b, nullptr, outB, NB);
        }
    }

    // ---- gate n (g=2): conv input is r*h (rhbuf) ----
    {
        const int g = 2;
        gemm64_kernel<<<gridA, 256, 0, stream>>>(rh_a, gws + (g * 3 + 0) * 4096, gas + (g * 3 + 0) * 64, xs0, als0, NA);
        gemm64_kernel<<<gridA, 256, 0, stream>>>(rh_a, gws + (g * 3 + 1) * 4096, gas + (g * 3 + 1) * 64, xs1, als1, NA);
        gemm64_kernel<<<gridB, 256, 0, stream>>>(rh_b, gws + (g * 3 + 2) * 4096, gas + (g * 3 + 2) * 64, xs2, als2, NB);
        ald_kernel<<<gridA, 256, 0, stream>>>(rh_a, gwd + (g * 3 + 0) * 4096, gad + (g * 3 + 0) * 64, ald0, NA);
        ald_kernel<<<gridB, 256, 0, stream>>>(rh_b, gwd + (g * 3 + 1) * 4096, gad + (g * 3 + 1) * 64, ald1, NB);
        ald_kernel<<<gridA, 256, 0, stream>>>(rh_a, gwd + (g * 3 + 2) * 4096, gad + (g * 3 + 2) * 64, ald2, NA);

        aggregate_kernel<2, 1><<<gridA, 256, 0, stream>>>(
            rp0, cnt0, csr0, als0, ald0, xs0, gb + (g * 3 + 0) * 64,
            rp2, cnt2, csr2, als2, ald2, xs2, gb + (g * 3 + 2) * 64,
            x_a, Wx + (g * 2 + 0) * 2048, bx + (g * 2 + 0) * 64,
            h_a, zbuf, out, NA);
        aggregate_kernel<2, 0><<<gridB, 256, 0, stream>>>(
            rp1, cnt1, csr1, als1, ald1, xs1, gb + (g * 3 + 1) * 64,
            nullptr, nullptr, nullptr, nullptr, nullptr, nullptr, nullptr,
            x_b, Wx + (g * 2 + 1) * 2048, bx + (g * 2 + 1) * 64,
            h_b, zbuf + (size_t)NA * 64, out + (size_t)NA * 64, NB);
    }
}

// Round 2
// 816.728 us; speedup vs baseline: 1.9102x; 1.9102x over previous
//
#include <hip/hip_runtime.h>
#include <hip/hip_bf16.h>
#include <cstddef>
#include <cstdint>

#define NA 50000
#define NB 10000
#define D_IN 32
#define D_OUT 64
#define EA2A 800000
#define EA2B 400000
#define EB2A 400000

typedef unsigned int u32;
typedef unsigned short u16;

// ---------------- wave helpers ----------------
__device__ __forceinline__ float wredmax(float v) {
#pragma unroll
    for (int off = 32; off; off >>= 1) v = fmaxf(v, __shfl_xor(v, off, 64));
    return v;
}
__device__ __forceinline__ float wredsum(float v) {
#pragma unroll
    for (int off = 32; off; off >>= 1) v += __shfl_xor(v, off, 64);
    return v;
}
__device__ __forceinline__ u32 bf16r(float x) {          // round-to-nearest-even bf16 bits
    u32 u = __float_as_uint(x);
    u += 0x7fffu + ((u >> 16) & 1u);
    return u >> 16;
}
__device__ __forceinline__ float ubf(u32 bits) { return __uint_as_float(bits); }

// ---------------- fused GEMM: xs[m] = H @ W[m] (bf16 out), als[m] = xs[m]@As[m],
// ---------------- ald[v] = H @ (WD[v] @ AD[v])
struct GemmArgs {
    const float* H; int N;
    const float* W[4];
    const float* As[4];
    void* XS[4];          // PACK==2: u32[N*64] (lo=even m, hi=odd m); PACK==1: u16[N*64]
    float* ALS[4];        // pre-offset; element at row*PACK
    const float* WD[4];
    const float* AD[4];
    float* ALD[4];        // pre-offset; element at row*PACK
};

template <int NM, int NV, int PACK>
__global__ void __launch_bounds__(256) gemm_fused(GemmArgs a)
{
    __shared__ float Wsh[NM * 4096];
    __shared__ float WDsh[NV * 64];
    int t = threadIdx.x;
#pragma unroll
    for (int m = 0; m < NM; ++m) {
        const float4* src = (const float4*)a.W[m];
        float4* dst = (float4*)&Wsh[m * 4096];
        for (int i = t; i < 1024; i += 256) dst[i] = src[i];
    }
    if (t < NV * 64) {
        int v = t >> 6, k = t & 63;
        const float* wd = a.WD[v] + k * 64;
        const float* ad = a.AD[v];
        float s = 0.f;
#pragma unroll 16
        for (int d = 0; d < 64; ++d) s = fmaf(wd[d], ad[d], s);
        WDsh[t] = s;
    }
    __syncthreads();
    int lane = t & 63, wid = t >> 6, wpb = blockDim.x >> 6;
    float asv[NM];
#pragma unroll
    for (int m = 0; m < NM; ++m) asv[m] = a.As[m][lane];
    int wgid = blockIdx.x * wpb + wid;
    int nw = gridDim.x * wpb;
    for (int r0 = wgid * 2; r0 < a.N; r0 += nw * 2) {
        int r1 = r0 + 1;
        bool has1 = r1 < a.N;
        float h0 = a.H[(size_t)r0 * 64 + lane];
        float h1 = has1 ? a.H[(size_t)r1 * 64 + lane] : 0.f;
        float acc[NM][2];
#pragma unroll
        for (int m = 0; m < NM; ++m) { acc[m][0] = 0.f; acc[m][1] = 0.f; }
#pragma unroll 16
        for (int k = 0; k < 64; ++k) {
            float hk0 = __shfl(h0, k, 64);
            float hk1 = __shfl(h1, k, 64);
#pragma unroll
            for (int m = 0; m < NM; ++m) {
                float w = Wsh[m * 4096 + k * 64 + lane];
                acc[m][0] = fmaf(hk0, w, acc[m][0]);
                acc[m][1] = fmaf(hk1, w, acc[m][1]);
            }
        }
        if (PACK == 2) {
#pragma unroll
            for (int m = 0; m < NM; m += 2) {
                u32* xo = (u32*)a.XS[m];
                xo[(size_t)r0 * 64 + lane] = bf16r(acc[m][0]) | (bf16r(acc[m + 1][0]) << 16);
                if (has1) xo[(size_t)r1 * 64 + lane] = bf16r(acc[m][1]) | (bf16r(acc[m + 1][1]) << 16);
            }
        } else {
#pragma unroll
            for (int m = 0; m < NM; ++m) {
                u16* xo = (u16*)a.XS[m];
                xo[(size_t)r0 * 64 + lane] = (u16)bf16r(acc[m][0]);
                if (has1) xo[(size_t)r1 * 64 + lane] = (u16)bf16r(acc[m][1]);
            }
        }
#pragma unroll
        for (int m = 0; m < NM; ++m) {
            float v0 = wredsum(acc[m][0] * asv[m]);
            float v1 = wredsum(acc[m][1] * asv[m]);
            if (lane == 0) {
                a.ALS[m][(size_t)r0 * PACK] = v0;
                if (has1) a.ALS[m][(size_t)r1 * PACK] = v1;
            }
        }
#pragma unroll
        for (int v = 0; v < NV; ++v) {
            float q0 = wredsum(h0 * WDsh[v * 64 + lane]);
            float q1 = wredsum(h1 * WDsh[v * 64 + lane]);
            if (lane == 0) {
                a.ALD[v][(size_t)r0 * PACK] = q0;
                if (has1) a.ALD[v][(size_t)r1 * PACK] = q1;
            }
        }
    }
}

// ---------------- CSR build ----------------
__global__ void hist_kernel(const int* __restrict__ dst, int* __restrict__ cnt, int E)
{
    for (int i = blockIdx.x * blockDim.x + threadIdx.x; i < E; i += gridDim.x * blockDim.x)
        atomicAdd(&cnt[dst[i]], 1);
}

__global__ void scan_partial(const int* __restrict__ cnt, int* __restrict__ bsum, int N)
{
    __shared__ int sd[256];
    int t = threadIdx.x;
    int i = blockIdx.x * 256 + t;
    sd[t] = (i < N) ? cnt[i] : 0;
    __syncthreads();
    for (int off = 128; off; off >>= 1) {
        if (t < off) sd[t] += sd[t + off];
        __syncthreads();
    }
    if (t == 0) bsum[blockIdx.x] = sd[0];
}

__global__ void scan_tops(int* bsum, int nb)
{
    if (threadIdx.x == 0 && blockIdx.x == 0) {
        int run = 0;
        for (int b = 0; b < nb; ++b) { int v = bsum[b]; bsum[b] = run; run += v; }
    }
}

__global__ void scan_final(const int* __restrict__ cnt, const int* __restrict__ bsum,
                           int* __restrict__ rowptr, int N)
{
    __shared__ int sd[256];
    int t = threadIdx.x;
    int i = blockIdx.x * 256 + t;
    int v = (i < N) ? cnt[i] : 0;
    sd[t] = v;
    __syncthreads();
    for (int off = 1; off < 256; off <<= 1) {
        int add = (t >= off) ? sd[t - off] : 0;
        __syncthreads();
        sd[t] += add;
        __syncthreads();
    }
    if (i < N) rowptr[i] = bsum[blockIdx.x] + sd[t] - v;
}

__global__ void csr_fill(const int* __restrict__ esrc, const int* __restrict__ edst,
                         const int* __restrict__ rowptr, int* __restrict__ fpos,
                         int* __restrict__ csrc, int E)
{
    for (int i = blockIdx.x * blockDim.x + threadIdx.x; i < E; i += gridDim.x * blockDim.x) {
        int d = edst[i];
        int p = atomicAdd(&fpos[d], 1);
        csrc[rowptr[d] + p] = esrc[i];
    }
}

// ---------------- fused z+r GAT contribution (bf16-packed xs, MLP-8 gathers) ----
__device__ __forceinline__ void gat_zr(int i, int lane,
        const int* __restrict__ rp, const int* __restrict__ cnt, const int* __restrict__ src,
        const float2* __restrict__ als, const float2* __restrict__ ald,
        const u32* __restrict__ xs, float& oz, float& orr)
{
    int beg = rp[i];
    int deg = cnt[i];
    if (deg == 0) return;
    float2 ad = ald[i];
    float mz = -1e30f, mr = -1e30f, sz = 0.f, sr = 0.f, az = 0.f, ar = 0.f;
    for (int base = 0; base < deg; base += 64) {
        int j = base + lane;
        int sj = 0;
        float ez = -1e30f, er = -1e30f;
        if (j < deg) {
            sj = src[beg + j];
            float2 al = als[sj];
            float tz = al.x + ad.x; ez = (tz > 0.f) ? tz : 0.2f * tz;
            float tr = al.y + ad.y; er = (tr > 0.f) ? tr : 0.2f * tr;
        }
        float cmz = wredmax(ez);
        float cmr = wredmax(er);
        if (cmz > mz) { float s = __expf(mz - cmz); az *= s; sz *= s; mz = cmz; }
        if (cmr > mr) { float s = __expf(mr - cmr); ar *= s; sr *= s; mr = cmr; }
        float pz = (j < deg) ? __expf(ez - mz) : 0.f;
        float pr = (j < deg) ? __expf(er - mr) : 0.f;
        sz += wredsum(pz);
        sr += wredsum(pr);
        int c = deg - base; if (c > 64) c = 64;
        int full = c & ~7;
        for (int b = 0; b < full; b += 8) {
            int sv[8]; float pzv[8], prv[8];
#pragma unroll
            for (int u = 0; u < 8; ++u) {
                sv[u] = __shfl(sj, b + u, 64);
                pzv[u] = __shfl(pz, b + u, 64);
                prv[u] = __shfl(pr, b + u, 64);
            }
            u32 vv[8];
#pragma unroll
            for (int u = 0; u < 8; ++u) vv[u] = xs[(size_t)sv[u] * 64 + lane];
#pragma unroll
            for (int u = 0; u < 8; ++u) {
                az = fmaf(pzv[u], ubf(vv[u] << 16), az);
                ar = fmaf(prv[u], ubf(vv[u] & 0xffff0000u), ar);
            }
        }
        for (int b = full; b < c; ++b) {
            int sv = __shfl(sj, b, 64);
            float pzv = __shfl(pz, b, 64);
            float prv = __shfl(pr, b, 64);
            u32 v = xs[(size_t)sv * 64 + lane];
            az = fmaf(pzv, ubf(v << 16), az);
            ar = fmaf(prv, ubf(v & 0xffff0000u), ar);
        }
    }
    oz += az / (sz + 1e-16f);
    orr += ar / (sr + 1e-16f);
}

// ---------------- single-gate GAT contribution (bf16 xs) ----------------
__device__ __forceinline__ float gat_n(int i, int lane,
        const int* __restrict__ rp, const int* __restrict__ cnt, const int* __restrict__ src,
        const float* __restrict__ als, const float* __restrict__ ald,
        const u16* __restrict__ xs)
{
    int beg = rp[i];
    int deg = cnt[i];
    if (deg == 0) return 0.f;
    float aldi = ald[i];
    float m = -1e30f, ssum = 0.f, acc = 0.f;
    for (int base = 0; base < deg; base += 64) {
        int j = base + lane;
        int sj = 0;
        float e = -1e30f;
        if (j < deg) {
            sj = src[beg + j];
            float tv = als[sj] + aldi;
            e = (tv > 0.f) ? tv : 0.2f * tv;
        }
        float cm = wredmax(e);
        if (cm > m) { float s = __expf(m - cm); acc *= s; ssum *= s; m = cm; }
        float p = (j < deg) ? __expf(e - m) : 0.f;
        ssum += wredsum(p);
        int c = deg - base; if (c > 64) c = 64;
        int full = c & ~7;
        for (int b = 0; b < full; b += 8) {
            int sv[8]; float pv[8];
#pragma unroll
            for (int u = 0; u < 8; ++u) {
                sv[u] = __shfl(sj, b + u, 64);
                pv[u] = __shfl(p, b + u, 64);
            }
            u16 vv[8];
#pragma unroll
            for (int u = 0; u < 8; ++u) vv[u] = xs[(size_t)sv[u] * 64 + lane];
#pragma unroll
            for (int u = 0; u < 8; ++u) acc = fmaf(pv[u], ubf((u32)vv[u] << 16), acc);
        }
        for (int b = full; b < c; ++b) {
            int sv = __shfl(sj, b, 64);
            float pv = __shfl(p, b, 64);
            u16 v = xs[(size_t)sv * 64 + lane];
            acc = fmaf(pv, ubf((u32)v << 16), acc);
        }
    }
    return acc / (ssum + 1e-16f);
}

// ---------------- aggregate: z+r fused ----------------
template <int TWOET>
__global__ void __launch_bounds__(256) aggregate_zr(
    const int* __restrict__ rp1, const int* __restrict__ cnt1, const int* __restrict__ src1,
    const float2* __restrict__ als1, const float2* __restrict__ ald1, const u32* __restrict__ xs1,
    const float* __restrict__ gbz1, const float* __restrict__ gbr1,
    const int* __restrict__ rp2, const int* __restrict__ cnt2, const int* __restrict__ src2,
    const float2* __restrict__ als2, const float2* __restrict__ ald2, const u32* __restrict__ xs2,
    const float* __restrict__ gbz2, const float* __restrict__ gbr2,
    const float* __restrict__ X,
    const float* __restrict__ WXz, const float* __restrict__ WXr,
    const float* __restrict__ BXz, const float* __restrict__ BXr,
    const float* __restrict__ H,
    float* __restrict__ ZOUT, float* __restrict__ RHOUT, int N)
{
    int t = threadIdx.x;
    int lane = t & 63, wid = t >> 6, wpb = blockDim.x >> 6;
    float wxcz[32], wxcr[32];
#pragma unroll
    for (int k = 0; k < 32; ++k) { wxcz[k] = WXz[k * 64 + lane]; wxcr[k] = WXr[k * 64 + lane]; }
    float cbz = gbz1[lane] + BXz[lane];
    float cbr = gbr1[lane] + BXr[lane];
    if (TWOET) { cbz += gbz2[lane]; cbr += gbr2[lane]; }
    for (int i = blockIdx.x * wpb + wid; i < N; i += gridDim.x * wpb) {
        float xv = (lane < 32) ? X[(size_t)i * 32 + lane] : 0.f;
        float pz = cbz, pr = cbr;
#pragma unroll
        for (int k = 0; k < 32; ++k) {
            float xk = __shfl(xv, k, 64);
            pz = fmaf(xk, wxcz[k], pz);
            pr = fmaf(xk, wxcr[k], pr);
        }
        gat_zr(i, lane, rp1, cnt1, src1, als1, ald1, xs1, pz, pr);
        if (TWOET) gat_zr(i, lane, rp2, cnt2, src2, als2, ald2, xs2, pz, pr);
        size_t o = (size_t)i * 64 + lane;
        float hv = H[o];
        ZOUT[o] = 1.f / (1.f + __expf(-pz));
        RHOUT[o] = (1.f / (1.f + __expf(-pr))) * hv;
    }
}

// ---------------- aggregate: n gate + GRU combine ----------------
template <int TWOET>
__global__ void __launch_bounds__(256) aggregate_n(
    const int* __restrict__ rp1, const int* __restrict__ cnt1, const int* __restrict__ src1,
    const float* __restrict__ als1, const float* __restrict__ ald1, const u16* __restrict__ xs1,
    const float* __restrict__ gb1,
    const int* __restrict__ rp2, const int* __restrict__ cnt2, const int* __restrict__ src2,
    const float* __restrict__ als2, const float* __restrict__ ald2, const u16* __restrict__ xs2,
    const float* __restrict__ gb2,
    const float* __restrict__ X, const float* __restrict__ WX, const float* __restrict__ BX,
    const float* __restrict__ H, const float* __restrict__ Z,
    float* __restrict__ OUT, int N)
{
    int t = threadIdx.x;
    int lane = t & 63, wid = t >> 6, wpb = blockDim.x >> 6;
    float wxc[32];
#pragma unroll
    for (int k = 0; k < 32; ++k) wxc[k] = WX[k * 64 + lane];
    float cb = gb1[lane] + BX[lane];
    if (TWOET) cb += gb2[lane];
    for (int i = blockIdx.x * wpb + wid; i < N; i += gridDim.x * wpb) {
        float xv = (lane < 32) ? X[(size_t)i * 32 + lane] : 0.f;
        float pre = cb;
#pragma unroll
        for (int k = 0; k < 32; ++k) pre = fmaf(__shfl(xv, k, 64), wxc[k], pre);
        pre += gat_n(i, lane, rp1, cnt1, src1, als1, ald1, xs1);
        if (TWOET) pre += gat_n(i, lane, rp2, cnt2, src2, als2, ald2, xs2);
        size_t o = (size_t)i * 64 + lane;
        float x2 = pre * 2.f;
        x2 = fminf(fmaxf(x2, -30.f), 30.f);
        float ex = __expf(x2);
        float nv = (ex - 1.f) / (ex + 1.f);
        float zv = Z[o];
        OUT[o] = (1.f - zv) * nv + zv * H[o];
    }
}

// ---------------- host side ----------------
extern "C" void kernel_launch(void* const* d_in, const int* in_sizes, int n_in,
                              void* d_out, int out_size, void* d_ws, size_t ws_size,
                              hipStream_t stream)
{
    (void)in_sizes; (void)n_in; (void)out_size; (void)ws_size;
    const float* x_a = (const float*)d_in[0];
    const float* x_b = (const float*)d_in[1];
    const float* h_a = (const float*)d_in[2];
    const float* h_b = (const float*)d_in[3];
    const float* Wx  = (const float*)d_in[4];
    const float* bx  = (const float*)d_in[5];
    const float* gws = (const float*)d_in[6];
    const float* gwd = (const float*)d_in[7];
    const float* gas = (const float*)d_in[8];
    const float* gad = (const float*)d_in[9];
    const float* gb  = (const float*)d_in[10];
    const int* ea2a_s = (const int*)d_in[11];
    const int* ea2a_d = (const int*)d_in[12];
    const int* ea2b_s = (const int*)d_in[13];
    const int* ea2b_d = (const int*)d_in[14];
    const int* eb2a_s = (const int*)d_in[15];
    const int* eb2a_d = (const int*)d_in[16];
    float* out = (float*)d_out;

    char* w = (char*)d_ws;
    auto alloc = [&](size_t bytes) -> char* {
        char* p = w;
        w += (bytes + 255) & ~(size_t)255;
        return p;
    };
    // xs block (zr phase uses u32[N*64]; n phase aliases as u16[N*64])
    char* xsblk = alloc((size_t)(NA + NA + NB) * 64 * 4);
    u32* xs_zr0 = (u32*)xsblk;
    u32* xs_zr1 = (u32*)(xsblk + (size_t)NA * 64 * 4);
    u32* xs_zr2 = (u32*)(xsblk + (size_t)(NA + NA) * 64 * 4);
    u16* xs_n0 = (u16*)xsblk;
    u16* xs_n1 = (u16*)(xsblk + (size_t)NA * 64 * 2);
    u16* xs_n2 = (u16*)(xsblk + (size_t)(NA + NA) * 64 * 2);
    // al block (zr: float2 per node; n aliases as float per node)
    char* alblk = alloc((size_t)(4 * NA + 2 * NB) * 2 * 4);
    float* als_zr0 = (float*)alblk;                                     // NA*2
    float* als_zr1 = als_zr0 + (size_t)NA * 2;                          // NA*2
    float* als_zr2 = als_zr1 + (size_t)NA * 2;                          // NB*2
    float* ald_zr0 = als_zr2 + (size_t)NB * 2;                          // NA*2
    float* ald_zr1 = ald_zr0 + (size_t)NA * 2;                          // NB*2
    float* ald_zr2 = ald_zr1 + (size_t)NB * 2;                          // NA*2
    float* als_n0 = (float*)alblk;                                      // NA
    float* als_n1 = als_n0 + NA;                                        // NA
    float* als_n2 = als_n1 + NA;                                        // NB
    float* ald_n0 = als_n2 + NB;                                        // NA
    float* ald_n1 = ald_n0 + NA;                                        // NB
    float* ald_n2 = ald_n1 + NB;                                        // NA
    float* zbuf  = (float*)alloc((size_t)(NA + NB) * 64 * 4);
    float* rhbuf = (float*)alloc((size_t)(NA + NB) * 64 * 4);
    char* zero_begin = w;
    int* cnt0 = (int*)alloc((size_t)NA * 4);
    int* cnt1 = (int*)alloc((size_t)NB * 4);
    int* cnt2 = (int*)alloc((size_t)NA * 4);
    int* fp0  = (int*)alloc((size_t)NA * 4);
    int* fp1  = (int*)alloc((size_t)NB * 4);
    int* fp2  = (int*)alloc((size_t)NA * 4);
    char* zero_end = w;
    int* rp0  = (int*)alloc((size_t)NA * 4);
    int* rp1  = (int*)alloc((size_t)NB * 4);
    int* rp2  = (int*)alloc((size_t)NA * 4);
    int* csr0 = (int*)alloc((size_t)EA2A * 4);
    int* csr1 = (int*)alloc((size_t)EA2B * 4);
    int* csr2 = (int*)alloc((size_t)EB2A * 4);
    int* bsum = (int*)alloc(256 * 4);

    const int nbA = (NA + 255) / 256;
    const int nbB = (NB + 255) / 256;

    // ---- CSR build ----
    hipMemsetAsync(zero_begin, 0, (size_t)(zero_end - zero_begin), stream);
    hist_kernel<<<1024, 256, 0, stream>>>(ea2a_d, cnt0, EA2A);
    hist_kernel<<<1024, 256, 0, stream>>>(ea2b_d, cnt1, EA2B);
    hist_kernel<<<1024, 256, 0, stream>>>(eb2a_d, cnt2, EB2A);

    scan_partial<<<nbA, 256, 0, stream>>>(cnt0, bsum, NA);
    scan_tops<<<1, 64, 0, stream>>>(bsum, nbA);
    scan_final<<<nbA, 256, 0, stream>>>(cnt0, bsum, rp0, NA);

    scan_partial<<<nbB, 256, 0, stream>>>(cnt1, bsum, NB);
    scan_tops<<<1, 64, 0, stream>>>(bsum, nbB);
    scan_final<<<nbB, 256, 0, stream>>>(cnt1, bsum, rp1, NB);

    scan_partial<<<nbA, 256, 0, stream>>>(cnt2, bsum, NA);
    scan_tops<<<1, 64, 0, stream>>>(bsum, nbA);
    scan_final<<<nbA, 256, 0, stream>>>(cnt2, bsum, rp2, NA);

    csr_fill<<<1024, 256, 0, stream>>>(ea2a_s, ea2a_d, rp0, fp0, csr0, EA2A);
    csr_fill<<<1024, 256, 0, stream>>>(ea2b_s, ea2b_d, rp1, fp1, csr1, EA2B);
    csr_fill<<<1024, 256, 0, stream>>>(eb2a_s, eb2a_d, rp2, fp2, csr2, EB2A);

    float* rh_a = rhbuf;
    float* rh_b = rhbuf + (size_t)NA * 64;
    float* z_a = zbuf;
    float* z_b = zbuf + (size_t)NA * 64;

    // ---- z+r GEMMs ----
    {
        GemmArgs a{};
        a.H = h_a; a.N = NA;
        // m0=(z,a2a) m1=(r,a2a) m2=(z,a2b) m3=(r,a2b)
        a.W[0] = gws + 0 * 4096; a.W[1] = gws + 3 * 4096; a.W[2] = gws + 1 * 4096; a.W[3] = gws + 4 * 4096;
        a.As[0] = gas + 0 * 64;  a.As[1] = gas + 3 * 64;  a.As[2] = gas + 1 * 64;  a.As[3] = gas + 4 * 64;
        a.XS[0] = xs_zr0; a.XS[1] = xs_zr0; a.XS[2] = xs_zr1; a.XS[3] = xs_zr1;
        a.ALS[0] = als_zr0; a.ALS[1] = als_zr0 + 1; a.ALS[2] = als_zr1; a.ALS[3] = als_zr1 + 1;
        // v0=(z,a2a dst) v1=(r,a2a dst) v2=(z,b2a dst) v3=(r,b2a dst)
        a.WD[0] = gwd + 0 * 4096; a.WD[1] = gwd + 3 * 4096; a.WD[2] = gwd + 2 * 4096; a.WD[3] = gwd + 5 * 4096;
        a.AD[0] = gad + 0 * 64;   a.AD[1] = gad + 3 * 64;   a.AD[2] = gad + 2 * 64;   a.AD[3] = gad + 5 * 64;
        a.ALD[0] = ald_zr0; a.ALD[1] = ald_zr0 + 1; a.ALD[2] = ald_zr2; a.ALD[3] = ald_zr2 + 1;
        gemm_fused<4, 4, 2><<<512, 256, 0, stream>>>(a);
    }
    {
        GemmArgs a{};
        a.H = h_b; a.N = NB;
        // m0=(z,b2a) m1=(r,b2a)
        a.W[0] = gws + 2 * 4096; a.W[1] = gws + 5 * 4096;
        a.As[0] = gas + 2 * 64;  a.As[1] = gas + 5 * 64;
        a.XS[0] = xs_zr2; a.XS[1] = xs_zr2;
        a.ALS[0] = als_zr2; a.ALS[1] = als_zr2 + 1;
        // v0=(z,a2b dst) v1=(r,a2b dst)
        a.WD[0] = gwd + 1 * 4096; a.WD[1] = gwd + 4 * 4096;
        a.AD[0] = gad + 1 * 64;   a.AD[1] = gad + 4 * 64;
        a.ALD[0] = ald_zr1; a.ALD[1] = ald_zr1 + 1;
        gemm_fused<2, 2, 2><<<128, 256, 0, stream>>>(a);
    }

    const int gridA = (NA + 3) / 4;
    const int gridB = (NB + 3) / 4;

    // ---- z+r aggregation ----
    aggregate_zr<1><<<gridA, 256, 0, stream>>>(
        rp0, cnt0, csr0, (const float2*)als_zr0, (const float2*)ald_zr0, xs_zr0,
        gb + 0 * 64, gb + 3 * 64,
        rp2, cnt2, csr2, (const float2*)als_zr2, (const float2*)ald_zr2, xs_zr2,
        gb + 2 * 64, gb + 5 * 64,
        x_a, Wx + 0 * 2048, Wx + 2 * 2048, bx + 0 * 64, bx + 2 * 64,
        h_a, z_a, rh_a, NA);
    aggregate_zr<0><<<gridB, 256, 0, stream>>>(
        rp1, cnt1, csr1, (const float2*)als_zr1, (const float2*)ald_zr1, xs_zr1,
        gb + 1 * 64, gb + 4 * 64,
        nullptr, nullptr, nullptr, nullptr, nullptr, nullptr, nullptr, nullptr,
        x_b, Wx + 1 * 2048, Wx + 3 * 2048, bx + 1 * 64, bx + 3 * 64,
        h_b, z_b, rh_b, NB);

    // ---- n GEMMs (input rh) ----
    {
        GemmArgs a{};
        a.H = rh_a; a.N = NA;
        // m0=(n,a2a) m1=(n,a2b)
        a.W[0] = gws + 6 * 4096; a.W[1] = gws + 7 * 4096;
        a.As[0] = gas + 6 * 64;  a.As[1] = gas + 7 * 64;
        a.XS[0] = xs_n0; a.XS[1] = xs_n1;
        a.ALS[0] = als_n0; a.ALS[1] = als_n1;
        // v0=(n,a2a dst) v1=(n,b2a dst)
        a.WD[0] = gwd + 6 * 4096; a.WD[1] = gwd + 8 * 4096;
        a.AD[0] = gad + 6 * 64;   a.AD[1] = gad + 8 * 64;
        a.ALD[0] = ald_n0; a.ALD[1] = ald_n2;
        gemm_fused<2, 2, 1><<<512, 256, 0, stream>>>(a);
    }
    {
        GemmArgs a{};
        a.H = rh_b; a.N = NB;
        // m0=(n,b2a)
        a.W[0] = gws + 8 * 4096;
        a.As[0] = gas + 8 * 64;
        a.XS[0] = xs_n2;
        a.ALS[0] = als_n2;
        // v0=(n,a2b dst)
        a.WD[0] = gwd + 7 * 4096;
        a.AD[0] = gad + 7 * 64;
        a.ALD[0] = ald_n1;
        gemm_fused<1, 1, 1><<<128, 256, 0, stream>>>(a);
    }

    // ---- n aggregation + GRU combine ----
    aggregate_n<1><<<gridA, 256, 0, stream>>>(
        rp0, cnt0, csr0, als_n0, ald_n0, xs_n0, gb + 6 * 64,
        rp2, cnt2, csr2, als_n2, ald_n2, xs_n2, gb + 8 * 64,
        x_a, Wx + 4 * 2048, bx + 4 * 64,
        h_a, z_a, out, NA);
    aggregate_n<0><<<gridB, 256, 0, stream>>>(
        rp1, cnt1, csr1, als_n1, ald_n1, xs_n1, gb + 7 * 64,
        nullptr, nullptr, nullptr, nullptr, nullptr, nullptr, nullptr,
        x_b, Wx + 5 * 2048, bx + 5 * 64,
        h_b, z_b, out + (size_t)NA * 64, NB);
}

// Round 5
// 612.267 us; speedup vs baseline: 2.5481x; 1.3339x over previous
//
#include <hip/hip_runtime.h>
#include <hip/hip_bf16.h>
#include <cstddef>
#include <cstdint>

#define NA 50000
#define NB 10000
#define D_IN 32
#define D_OUT 64
#define EA2A 800000
#define EA2B 400000
#define EB2A 400000
#define NCAT (NA + NB + NA)
#define ETOT (EA2A + EA2B + EB2A)

typedef unsigned int u32;
typedef unsigned short u16;

// ---------------- helpers ----------------
__device__ __forceinline__ u32 bf16r(float x) {          // round-to-nearest-even bf16 bits
    u32 u = __float_as_uint(x);
    u += 0x7fffu + ((u >> 16) & 1u);
    return u >> 16;
}
__device__ __forceinline__ float ubf(u32 bits) { return __uint_as_float(bits); }
__device__ __forceinline__ float sigm(float x) { return 1.f / (1.f + __expf(-x)); }

template <int CTRL, int RM>
__device__ __forceinline__ float dppf(float v) {
    return __int_as_float(__builtin_amdgcn_update_dpp(0, __float_as_int(v), CTRL, RM, 0xf, true));
}
// full-wave sum, result broadcast via readlane(63) -> uniform
__device__ __forceinline__ float wsum64(float v) {
    v += dppf<0x111, 0xf>(v);   // row_shr:1
    v += dppf<0x112, 0xf>(v);   // row_shr:2
    v += dppf<0x114, 0xf>(v);   // row_shr:4
    v += dppf<0x118, 0xf>(v);   // row_shr:8
    v += dppf<0x142, 0xa>(v);   // row_bcast15 into rows 1,3
    v += dppf<0x143, 0xc>(v);   // row_bcast31 into rows 2,3
    return __int_as_float(__builtin_amdgcn_readlane(__float_as_int(v), 63));
}
// full-wave max clamped at >= 0 (bound_ctrl injects 0). Safe: softmax is shift-invariant,
// m only needs >= true max for exp-range safety.
__device__ __forceinline__ float wmax64(float v) {
    v = fmaxf(v, dppf<0x111, 0xf>(v));
    v = fmaxf(v, dppf<0x112, 0xf>(v));
    v = fmaxf(v, dppf<0x114, 0xf>(v));
    v = fmaxf(v, dppf<0x118, 0xf>(v));
    v = fmaxf(v, dppf<0x142, 0xa>(v));
    v = fmaxf(v, dppf<0x143, 0xc>(v));
    return __int_as_float(__builtin_amdgcn_readlane(__float_as_int(v), 63));
}

// ---------------- fused GEMM: xs[m] = H @ W[m] (bf16 out), als[m], ald[v] ----
struct GemmArgs {
    const float* H; int N;
    const float* W[4];
    const float* As[4];
    void* XS[4];          // PACK==2: u32[N*64] (lo=even m, hi=odd m); PACK==1: u16[N*64]
    float* ALS[4];        // pre-offset; element at row*PACK
    const float* WD[4];
    const float* AD[4];
    float* ALD[4];        // pre-offset; element at row*PACK
};

template <int NM, int NV, int PACK>
__global__ void __launch_bounds__(256) gemm_fused(GemmArgs a)
{
    __shared__ float Wsh[NM * 4096];
    __shared__ float WDsh[NV * 64];
    int t = threadIdx.x;
#pragma unroll
    for (int m = 0; m < NM; ++m) {
        const float4* src = (const float4*)a.W[m];
        float4* dst = (float4*)&Wsh[m * 4096];
        for (int i = t; i < 1024; i += 256) dst[i] = src[i];
    }
    if (t < NV * 64) {
        int v = t >> 6, k = t & 63;
        const float* wd = a.WD[v] + k * 64;
        const float* ad = a.AD[v];
        float s = 0.f;
#pragma unroll 16
        for (int d = 0; d < 64; ++d) s = fmaf(wd[d], ad[d], s);
        WDsh[t] = s;
    }
    __syncthreads();
    int lane = t & 63, wid = t >> 6, wpb = blockDim.x >> 6;
    float asv[NM];
#pragma unroll
    for (int m = 0; m < NM; ++m) asv[m] = a.As[m][lane];
    int wgid = blockIdx.x * wpb + wid;
    int nw = gridDim.x * wpb;
    for (int r0 = wgid * 2; r0 < a.N; r0 += nw * 2) {
        int r1 = r0 + 1;
        bool has1 = r1 < a.N;
        float h0 = a.H[(size_t)r0 * 64 + lane];
        float h1 = has1 ? a.H[(size_t)r1 * 64 + lane] : 0.f;
        float acc[NM][2];
#pragma unroll
        for (int m = 0; m < NM; ++m) { acc[m][0] = 0.f; acc[m][1] = 0.f; }
#pragma unroll 16
        for (int k = 0; k < 64; ++k) {
            float hk0 = __shfl(h0, k, 64);
            float hk1 = __shfl(h1, k, 64);
#pragma unroll
            for (int m = 0; m < NM; ++m) {
                float w = Wsh[m * 4096 + k * 64 + lane];
                acc[m][0] = fmaf(hk0, w, acc[m][0]);
                acc[m][1] = fmaf(hk1, w, acc[m][1]);
            }
        }
        if (PACK == 2) {
#pragma unroll
            for (int m = 0; m < NM; m += 2) {
                u32* xo = (u32*)a.XS[m];
                xo[(size_t)r0 * 64 + lane] = bf16r(acc[m][0]) | (bf16r(acc[m + 1][0]) << 16);
                if (has1) xo[(size_t)r1 * 64 + lane] = bf16r(acc[m][1]) | (bf16r(acc[m + 1][1]) << 16);
            }
        } else {
#pragma unroll
            for (int m = 0; m < NM; ++m) {
                u16* xo = (u16*)a.XS[m];
                xo[(size_t)r0 * 64 + lane] = (u16)bf16r(acc[m][0]);
                if (has1) xo[(size_t)r1 * 64 + lane] = (u16)bf16r(acc[m][1]);
            }
        }
#pragma unroll
        for (int m = 0; m < NM; ++m) {
            float v0 = wsum64(acc[m][0] * asv[m]);
            float v1 = wsum64(acc[m][1] * asv[m]);
            if (lane == 0) {
                a.ALS[m][(size_t)r0 * PACK] = v0;
                if (has1) a.ALS[m][(size_t)r1 * PACK] = v1;
            }
        }
#pragma unroll
        for (int v = 0; v < NV; ++v) {
            float q0 = wsum64(h0 * WDsh[v * 64 + lane]);
            float q1 = wsum64(h1 * WDsh[v * 64 + lane]);
            if (lane == 0) {
                a.ALD[v][(size_t)r0 * PACK] = q0;
                if (has1) a.ALD[v][(size_t)r1 * PACK] = q1;
            }
        }
    }
}

// ---------------- dense precompute: d*(node,dim) = x @ Wx[g] + bx + sum(gat_b) ----
__global__ void __launch_bounds__(256) gemm_x_k(
    const float* __restrict__ xA, const float* __restrict__ xB,
    const float* __restrict__ Wx, const float* __restrict__ bx, const float* __restrict__ gb,
    u32* __restrict__ dzrA, u32* __restrict__ dzrB,
    u16* __restrict__ dnA, u16* __restrict__ dnB)
{
    __shared__ float Wsh[3 * 2048];
    __shared__ float cb[3 * 64];
    int t = threadIdx.x;
    int blk = blockIdx.x;
    bool isA = blk < (NA / 8);
    int ty = isA ? 0 : 1;
#pragma unroll
    for (int g = 0; g < 3; ++g) {
        const float4* s = (const float4*)(Wx + (size_t)(g * 2 + ty) * 2048);
        float4* d = (float4*)&Wsh[g * 2048];
        for (int i = t; i < 512; i += 256) d[i] = s[i];
    }
    if (t < 192) {
        int g = t >> 6, d = t & 63;
        float c = bx[(g * 2 + ty) * 64 + d];
        if (isA) c += gb[(g * 3 + 0) * 64 + d] + gb[(g * 3 + 2) * 64 + d];
        else     c += gb[(g * 3 + 1) * 64 + d];
        cb[t] = c;
    }
    __syncthreads();
    int lane = t & 63, wid = t >> 6;
    const float* X = isA ? xA : xB;
    int N = isA ? NA : NB;
    int rbase = (isA ? blk : blk - NA / 8) * 8 + wid * 2;
    float cz = cb[lane], cr = cb[64 + lane], cn = cb[128 + lane];
#pragma unroll
    for (int rr = 0; rr < 2; ++rr) {
        int r = rbase + rr;
        if (r >= N) break;
        float xv = (lane < 32) ? X[(size_t)r * 32 + lane] : 0.f;
        float az = cz, ar = cr, an = cn;
#pragma unroll
        for (int k = 0; k < 32; ++k) {
            float xk = __shfl(xv, k, 64);
            az = fmaf(xk, Wsh[k * 64 + lane], az);
            ar = fmaf(xk, Wsh[2048 + k * 64 + lane], ar);
            an = fmaf(xk, Wsh[4096 + k * 64 + lane], an);
        }
        u32 zr = bf16r(az) | (bf16r(ar) << 16);
        u16 nn = (u16)bf16r(an);
        if (isA) { dzrA[(size_t)r * 64 + lane] = zr; dnA[(size_t)r * 64 + lane] = nn; }
        else     { dzrB[(size_t)r * 64 + lane] = zr; dnB[(size_t)r * 64 + lane] = nn; }
    }
}

// ---------------- unified CSR build ----------------
__global__ void hist_k(const int* __restrict__ d0, const int* __restrict__ d1,
                       const int* __restrict__ d2, int* __restrict__ cnt)
{
    for (int e = blockIdx.x * blockDim.x + threadIdx.x; e < ETOT; e += gridDim.x * blockDim.x) {
        int g;
        if (e < EA2A) g = d0[e];
        else if (e < EA2A + EA2B) g = NA + d1[e - EA2A];
        else g = NA + NB + d2[e - EA2A - EA2B];
        atomicAdd(&cnt[g], 1);
    }
}

__global__ void scan_partial(const int* __restrict__ cnt, int* __restrict__ bsum, int N)
{
    __shared__ int sd[256];
    int t = threadIdx.x;
    int i = blockIdx.x * 256 + t;
    sd[t] = (i < N) ? cnt[i] : 0;
    __syncthreads();
    for (int off = 128; off; off >>= 1) {
        if (t < off) sd[t] += sd[t + off];
        __syncthreads();
    }
    if (t == 0) bsum[blockIdx.x] = sd[0];
}

__global__ void scan_tops(int* bsum, int nb)
{
    if (threadIdx.x == 0 && blockIdx.x == 0) {
        int run = 0;
        for (int b = 0; b < nb; ++b) { int v = bsum[b]; bsum[b] = run; run += v; }
    }
}

__global__ void scan_final(const int* __restrict__ cnt, const int* __restrict__ bsum,
                           int* __restrict__ rowptr, int N)
{
    __shared__ int sd[256];
    int t = threadIdx.x;
    int i = blockIdx.x * 256 + t;
    int v = (i < N) ? cnt[i] : 0;
    sd[t] = v;
    __syncthreads();
    for (int off = 1; off < 256; off <<= 1) {
        int add = (t >= off) ? sd[t - off] : 0;
        __syncthreads();
        sd[t] += add;
        __syncthreads();
    }
    if (i < N) rowptr[i] = bsum[blockIdx.x] + sd[t] - v;
}

__global__ void fill_k(const int* __restrict__ s0, const int* __restrict__ d0,
                       const int* __restrict__ s1, const int* __restrict__ d1,
                       const int* __restrict__ s2, const int* __restrict__ d2,
                       const int* __restrict__ rp, int* __restrict__ fp, int* __restrict__ csr)
{
    for (int e = blockIdx.x * blockDim.x + threadIdx.x; e < ETOT; e += gridDim.x * blockDim.x) {
        int g, s;
        if (e < EA2A) { g = d0[e]; s = s0[e]; }
        else if (e < EA2A + EA2B) { int k = e - EA2A; g = NA + d1[k]; s = s1[k]; }
        else { int k = e - EA2A - EA2B; g = NA + NB + d2[k]; s = s2[k]; }
        int p = atomicAdd(&fp[g], 1);
        csr[rp[g] + p] = s;
    }
}

// ---------------- GAT per-edge-type contributions ----------------
__device__ __forceinline__ void zr_fma(float az[4], float ar[4], uint4 v, float pz, float pr) {
    az[0] = fmaf(pz, ubf(v.x << 16), az[0]); ar[0] = fmaf(pr, ubf(v.x & 0xffff0000u), ar[0]);
    az[1] = fmaf(pz, ubf(v.y << 16), az[1]); ar[1] = fmaf(pr, ubf(v.y & 0xffff0000u), ar[1]);
    az[2] = fmaf(pz, ubf(v.z << 16), az[2]); ar[2] = fmaf(pr, ubf(v.z & 0xffff0000u), ar[2]);
    az[3] = fmaf(pz, ubf(v.w << 16), az[3]); ar[3] = fmaf(pr, ubf(v.w & 0xffff0000u), ar[3]);
}

__device__ __forceinline__ void gat_zr_et(
    int gnode, int inode, int lane, int sub, int grp,
    const int* __restrict__ rp, const int* __restrict__ cnt, const int* __restrict__ csr,
    const float2* __restrict__ als, const float2* __restrict__ ald,
    const uint4* __restrict__ xs,
    float oz[4], float orr[4])
{
    int deg = cnt[gnode];
    if (deg <= 0) return;
    int beg = rp[gnode];
    float2 ad = ald[inode];
    float mz = 0.f, mr = 0.f, sz = 0.f, sr = 0.f;
    float az[4] = {0.f, 0.f, 0.f, 0.f}, ar[4] = {0.f, 0.f, 0.f, 0.f};
    for (int base = 0; base < deg; base += 64) {
        int j = base + lane;
        int sj = 0; float ez = -1e30f, er = -1e30f;
        if (j < deg) {
            sj = csr[beg + j];
            float2 al = als[sj];
            float tz = al.x + ad.x; ez = tz > 0.f ? tz : 0.2f * tz;
            float tr = al.y + ad.y; er = tr > 0.f ? tr : 0.2f * tr;
        }
        float cmz = wmax64(ez), cmr = wmax64(er);
        if (base == 0) { mz = cmz; mr = cmr; }
        else {
            if (cmz > mz) { float s = __expf(mz - cmz);
                az[0] *= s; az[1] *= s; az[2] *= s; az[3] *= s; sz *= s; mz = cmz; }
            if (cmr > mr) { float s = __expf(mr - cmr);
                ar[0] *= s; ar[1] *= s; ar[2] *= s; ar[3] *= s; sr *= s; mr = cmr; }
        }
        float pz = (j < deg) ? __expf(ez - mz) : 0.f;
        float pr = (j < deg) ? __expf(er - mr) : 0.f;
        sz += wsum64(pz);
        sr += wsum64(pr);
        u32 pk = (u32)sj | (bf16r(pz) << 16);   // invalid lanes: sj=0, pz=0 -> pk=0, contributes 0
        int c = deg - base; if (c > 64) c = 64;
        int b = 0;
        for (; b + 16 <= c; b += 16) {
            u32 k0 = (u32)__shfl((int)pk, b + grp, 64);
            u32 k1 = (u32)__shfl((int)pk, b + 4 + grp, 64);
            u32 k2 = (u32)__shfl((int)pk, b + 8 + grp, 64);
            u32 k3 = (u32)__shfl((int)pk, b + 12 + grp, 64);
            float q0 = __shfl(pr, b + grp, 64);
            float q1 = __shfl(pr, b + 4 + grp, 64);
            float q2 = __shfl(pr, b + 8 + grp, 64);
            float q3 = __shfl(pr, b + 12 + grp, 64);
            uint4 v0 = xs[(size_t)(k0 & 0xffffu) * 16 + sub];
            uint4 v1 = xs[(size_t)(k1 & 0xffffu) * 16 + sub];
            uint4 v2 = xs[(size_t)(k2 & 0xffffu) * 16 + sub];
            uint4 v3 = xs[(size_t)(k3 & 0xffffu) * 16 + sub];
            zr_fma(az, ar, v0, ubf(k0 & 0xffff0000u), q0);
            zr_fma(az, ar, v1, ubf(k1 & 0xffff0000u), q1);
            zr_fma(az, ar, v2, ubf(k2 & 0xffff0000u), q2);
            zr_fma(az, ar, v3, ubf(k3 & 0xffff0000u), q3);
        }
        // tail: 4-edge steps; overflow lanes carry pk=0 (p=0) -> harmless
        for (; b < c; b += 4) {
            u32 k0 = (u32)__shfl((int)pk, b + grp, 64);
            float q0 = __shfl(pr, b + grp, 64);
            uint4 v0 = xs[(size_t)(k0 & 0xffffu) * 16 + sub];
            zr_fma(az, ar, v0, ubf(k0 & 0xffff0000u), q0);
        }
    }
    float rz = 1.f / (sz + 1e-16f), rr = 1.f / (sr + 1e-16f);
    oz[0] = fmaf(az[0], rz, oz[0]); orr[0] = fmaf(ar[0], rr, orr[0]);
    oz[1] = fmaf(az[1], rz, oz[1]); orr[1] = fmaf(ar[1], rr, orr[1]);
    oz[2] = fmaf(az[2], rz, oz[2]); orr[2] = fmaf(ar[2], rr, orr[2]);
    oz[3] = fmaf(az[3], rz, oz[3]); orr[3] = fmaf(ar[3], rr, orr[3]);
}

__device__ __forceinline__ void n_fma(float a[4], uint2 v, float p) {
    a[0] = fmaf(p, ubf(v.x << 16), a[0]);
    a[1] = fmaf(p, ubf(v.x & 0xffff0000u), a[1]);
    a[2] = fmaf(p, ubf(v.y << 16), a[2]);
    a[3] = fmaf(p, ubf(v.y & 0xffff0000u), a[3]);
}

__device__ __forceinline__ void gat_n_et(
    int gnode, int inode, int lane, int sub, int grp,
    const int* __restrict__ rp, const int* __restrict__ cnt, const int* __restrict__ csr,
    const float* __restrict__ als, const float* __restrict__ ald,
    const uint2* __restrict__ xs,
    float oa[4])
{
    int deg = cnt[gnode];
    if (deg <= 0) return;
    int beg = rp[gnode];
    float ad = ald[inode];
    float m = 0.f, ss = 0.f;
    float ac[4] = {0.f, 0.f, 0.f, 0.f};
    for (int base = 0; base < deg; base += 64) {
        int j = base + lane;
        int sj = 0; float e = -1e30f;
        if (j < deg) {
            sj = csr[beg + j];
            float tv = als[sj] + ad;
            e = tv > 0.f ? tv : 0.2f * tv;
        }
        float cm = wmax64(e);
        if (base == 0) m = cm;
        else if (cm > m) {
            float s = __expf(m - cm);
            ac[0] *= s; ac[1] *= s; ac[2] *= s; ac[3] *= s; ss *= s; m = cm;
        }
        float p = (j < deg) ? __expf(e - m) : 0.f;
        ss += wsum64(p);
        u32 pk = (u32)sj | (bf16r(p) << 16);
        int c = deg - base; if (c > 64) c = 64;
        int b = 0;
        for (; b + 16 <= c; b += 16) {
            u32 k0 = (u32)__shfl((int)pk, b + grp, 64);
            u32 k1 = (u32)__shfl((int)pk, b + 4 + grp, 64);
            u32 k2 = (u32)__shfl((int)pk, b + 8 + grp, 64);
            u32 k3 = (u32)__shfl((int)pk, b + 12 + grp, 64);
            uint2 v0 = xs[(size_t)(k0 & 0xffffu) * 16 + sub];
            uint2 v1 = xs[(size_t)(k1 & 0xffffu) * 16 + sub];
            uint2 v2 = xs[(size_t)(k2 & 0xffffu) * 16 + sub];
            uint2 v3 = xs[(size_t)(k3 & 0xffffu) * 16 + sub];
            n_fma(ac, v0, ubf(k0 & 0xffff0000u));
            n_fma(ac, v1, ubf(k1 & 0xffff0000u));
            n_fma(ac, v2, ubf(k2 & 0xffff0000u));
            n_fma(ac, v3, ubf(k3 & 0xffff0000u));
        }
        for (; b < c; b += 4) {
            u32 k0 = (u32)__shfl((int)pk, b + grp, 64);
            uint2 v0 = xs[(size_t)(k0 & 0xffffu) * 16 + sub];
            n_fma(ac, v0, ubf(k0 & 0xffff0000u));
        }
    }
    float rs = 1.f / (ss + 1e-16f);
    oa[0] = fmaf(ac[0], rs, oa[0]);
    oa[1] = fmaf(ac[1], rs, oa[1]);
    oa[2] = fmaf(ac[2], rs, oa[2]);
    oa[3] = fmaf(ac[3], rs, oa[3]);
}

// ---------------- aggregate kernels (A and B merged) ----------------
struct ZrArgs {
    const int *rp, *cnt, *csr;
    const float2 *als0, *ald0, *als1, *ald1, *als2, *ald2;
    const uint4 *xs0, *xs1, *xs2;
    const u32 *dzrA, *dzrB;
    const float *hA, *hB;
    float *zA, *rhA, *zB, *rhB;
};

__global__ void __launch_bounds__(256) aggregate_zr_k(ZrArgs P)
{
    int t = threadIdx.x, lane = t & 63, wid = t >> 6;
    int sub = lane & 15, grp = lane >> 4;
    float oz[4] = {0.f, 0.f, 0.f, 0.f}, orr[4] = {0.f, 0.f, 0.f, 0.f};
    int blk = blockIdx.x;
    const u32* dzr; const float* Hp; float *Zp, *RHp;
    if (blk < NA / 4) {
        int i = blk * 4 + wid;
        gat_zr_et(i, i, lane, sub, grp, P.rp, P.cnt, P.csr, P.als0, P.ald0, P.xs0, oz, orr);
        gat_zr_et(NA + NB + i, i, lane, sub, grp, P.rp, P.cnt, P.csr, P.als2, P.ald2, P.xs2, oz, orr);
        dzr = P.dzrA + (size_t)i * 64; Hp = P.hA + (size_t)i * 64;
        Zp = P.zA + (size_t)i * 64; RHp = P.rhA + (size_t)i * 64;
    } else {
        int i = (blk - NA / 4) * 4 + wid;
        gat_zr_et(NA + i, i, lane, sub, grp, P.rp, P.cnt, P.csr, P.als1, P.ald1, P.xs1, oz, orr);
        dzr = P.dzrB + (size_t)i * 64; Hp = P.hB + (size_t)i * 64;
        Zp = P.zB + (size_t)i * 64; RHp = P.rhB + (size_t)i * 64;
    }
#pragma unroll
    for (int q = 0; q < 4; ++q) {
        oz[q] += __shfl_xor(oz[q], 16, 64); oz[q] += __shfl_xor(oz[q], 32, 64);
        orr[q] += __shfl_xor(orr[q], 16, 64); orr[q] += __shfl_xor(orr[q], 32, 64);
    }
    if (grp == 0) {
        uint4 d = *(const uint4*)(dzr + sub * 4);
        float4 h = *(const float4*)(Hp + sub * 4);
        float z0 = sigm(oz[0] + ubf(d.x << 16)), r0 = sigm(orr[0] + ubf(d.x & 0xffff0000u)) * h.x;
        float z1 = sigm(oz[1] + ubf(d.y << 16)), r1 = sigm(orr[1] + ubf(d.y & 0xffff0000u)) * h.y;
        float z2 = sigm(oz[2] + ubf(d.z << 16)), r2 = sigm(orr[2] + ubf(d.z & 0xffff0000u)) * h.z;
        float z3 = sigm(oz[3] + ubf(d.w << 16)), r3 = sigm(orr[3] + ubf(d.w & 0xffff0000u)) * h.w;
        *(float4*)(Zp + sub * 4) = make_float4(z0, z1, z2, z3);
        *(float4*)(RHp + sub * 4) = make_float4(r0, r1, r2, r3);
    }
}

struct NArgs {
    const int *rp, *cnt, *csr;
    const float *als0, *ald0, *als1, *ald1, *als2, *ald2;
    const uint2 *xs0, *xs1, *xs2;
    const u16 *dnA, *dnB;
    const float *hA, *hB, *zA, *zB;
    float *outA, *outB;
};

__global__ void __launch_bounds__(256) aggregate_n_k(NArgs P)
{
    int t = threadIdx.x, lane = t & 63, wid = t >> 6;
    int sub = lane & 15, grp = lane >> 4;
    float oa[4] = {0.f, 0.f, 0.f, 0.f};
    int blk = blockIdx.x;
    const u16* dn; const float *Hp, *Zp; float* Op;
    if (blk < NA / 4) {
        int i = blk * 4 + wid;
        gat_n_et(i, i, lane, sub, grp, P.rp, P.cnt, P.csr, P.als0, P.ald0, P.xs0, oa);
        gat_n_et(NA + NB + i, i, lane, sub, grp, P.rp, P.cnt, P.csr, P.als2, P.ald2, P.xs2, oa);
        dn = P.dnA + (size_t)i * 64; Hp = P.hA + (size_t)i * 64;
        Zp = P.zA + (size_t)i * 64; Op = P.outA + (size_t)i * 64;
    } else {
        int i = (blk - NA / 4) * 4 + wid;
        gat_n_et(NA + i, i, lane, sub, grp, P.rp, P.cnt, P.csr, P.als1, P.ald1, P.xs1, oa);
        dn = P.dnB + (size_t)i * 64; Hp = P.hB + (size_t)i * 64;
        Zp = P.zB + (size_t)i * 64; Op = P.outB + (size_t)i * 64;
    }
#pragma unroll
    for (int q = 0; q < 4; ++q) {
        oa[q] += __shfl_xor(oa[q], 16, 64); oa[q] += __shfl_xor(oa[q], 32, 64);
    }
    if (grp == 0) {
        uint2 d = *(const uint2*)(dn + sub * 4);
        float4 h = *(const float4*)(Hp + sub * 4);
        float4 zv = *(const float4*)(Zp + sub * 4);
        float pre[4];
        pre[0] = oa[0] + ubf(d.x << 16);
        pre[1] = oa[1] + ubf(d.x & 0xffff0000u);
        pre[2] = oa[2] + ubf(d.y << 16);
        pre[3] = oa[3] + ubf(d.y & 0xffff0000u);
        float o[4];
        float hh[4] = {h.x, h.y, h.z, h.w};
        float zz[4] = {zv.x, zv.y, zv.z, zv.w};
#pragma unroll
        for (int q = 0; q < 4; ++q) {
            float x2 = fminf(fmaxf(pre[q] * 2.f, -30.f), 30.f);
            float ex = __expf(x2);
            float nv = (ex - 1.f) / (ex + 1.f);
            o[q] = (1.f - zz[q]) * nv + zz[q] * hh[q];
        }
        *(float4*)(Op + sub * 4) = make_float4(o[0], o[1], o[2], o[3]);
    }
}

// ---------------- host side ----------------
extern "C" void kernel_launch(void* const* d_in, const int* in_sizes, int n_in,
                              void* d_out, int out_size, void* d_ws, size_t ws_size,
                              hipStream_t stream)
{
    (void)in_sizes; (void)n_in; (void)out_size; (void)ws_size;
    const float* x_a = (const float*)d_in[0];
    const float* x_b = (const float*)d_in[1];
    const float* h_a = (const float*)d_in[2];
    const float* h_b = (const float*)d_in[3];
    const float* Wx  = (const float*)d_in[4];
    const float* bx  = (const float*)d_in[5];
    const float* gws = (const float*)d_in[6];
    const float* gwd = (const float*)d_in[7];
    const float* gas = (const float*)d_in[8];
    const float* gad = (const float*)d_in[9];
    const float* gb  = (const float*)d_in[10];
    const int* ea2a_s = (const int*)d_in[11];
    const int* ea2a_d = (const int*)d_in[12];
    const int* ea2b_s = (const int*)d_in[13];
    const int* ea2b_d = (const int*)d_in[14];
    const int* eb2a_s = (const int*)d_in[15];
    const int* eb2a_d = (const int*)d_in[16];
    float* out = (float*)d_out;

    char* w = (char*)d_ws;
    auto alloc = [&](size_t bytes) -> char* {
        char* p = w;
        w += (bytes + 255) & ~(size_t)255;
        return p;
    };
    // xs block: zr phase u32[N*64]; n phase aliases low half as u16[N*64]
    char* xsblk = alloc((size_t)(NA + NA + NB) * 64 * 4);
    u32* xs_zr0 = (u32*)xsblk;
    u32* xs_zr1 = (u32*)(xsblk + (size_t)NA * 64 * 4);
    u32* xs_zr2 = (u32*)(xsblk + (size_t)(NA + NA) * 64 * 4);
    u16* xs_n0 = (u16*)xsblk;
    u16* xs_n1 = (u16*)(xsblk + (size_t)NA * 64 * 2);
    u16* xs_n2 = (u16*)(xsblk + (size_t)(NA + NA) * 64 * 2);
    // al block: zr float2 per node; n aliases as float per node
    char* alblk = alloc((size_t)(4 * NA + 2 * NB) * 2 * 4);
    float* als_zr0 = (float*)alblk;
    float* als_zr1 = als_zr0 + (size_t)NA * 2;
    float* als_zr2 = als_zr1 + (size_t)NA * 2;
    float* ald_zr0 = als_zr2 + (size_t)NB * 2;
    float* ald_zr1 = ald_zr0 + (size_t)NA * 2;
    float* ald_zr2 = ald_zr1 + (size_t)NB * 2;
    float* als_n0 = (float*)alblk;
    float* als_n1 = als_n0 + NA;
    float* als_n2 = als_n1 + NA;
    float* ald_n0 = als_n2 + NB;
    float* ald_n1 = ald_n0 + NA;
    float* ald_n2 = ald_n1 + NB;
    float* zbuf  = (float*)alloc((size_t)(NA + NB) * 64 * 4);
    float* rhbuf = (float*)alloc((size_t)(NA + NB) * 64 * 4);
    u32* dzrA = (u32*)alloc((size_t)NA * 64 * 4);
    u32* dzrB = (u32*)alloc((size_t)NB * 64 * 4);
    u16* dnA = (u16*)alloc((size_t)NA * 64 * 2);
    u16* dnB = (u16*)alloc((size_t)NB * 64 * 2);
    char* zero_begin = w;
    int* cnt = (int*)alloc((size_t)NCAT * 4);
    int* fp  = (int*)alloc((size_t)NCAT * 4);
    char* zero_end = w;
    int* rp  = (int*)alloc((size_t)NCAT * 4);
    int* csr = (int*)alloc((size_t)ETOT * 4);
    int* bsum = (int*)alloc(512 * 4);

    const int nbC = (NCAT + 255) / 256;

    // ---- CSR build (unified) ----
    (void)hipMemsetAsync(zero_begin, 0, (size_t)(zero_end - zero_begin), stream);
    hist_k<<<2048, 256, 0, stream>>>(ea2a_d, ea2b_d, eb2a_d, cnt);
    scan_partial<<<nbC, 256, 0, stream>>>(cnt, bsum, NCAT);
    scan_tops<<<1, 64, 0, stream>>>(bsum, nbC);
    scan_final<<<nbC, 256, 0, stream>>>(cnt, bsum, rp, NCAT);
    fill_k<<<2048, 256, 0, stream>>>(ea2a_s, ea2a_d, ea2b_s, ea2b_d, eb2a_s, eb2a_d, rp, fp, csr);

    // ---- dense precompute (all 3 gates, both node types) ----
    gemm_x_k<<<(NA + NB) / 8, 256, 0, stream>>>(x_a, x_b, Wx, bx, gb, dzrA, dzrB, dnA, dnB);

    float* rh_a = rhbuf;
    float* rh_b = rhbuf + (size_t)NA * 64;
    float* z_a = zbuf;
    float* z_b = zbuf + (size_t)NA * 64;

    // ---- z+r GEMMs ----
    {
        GemmArgs a{};
        a.H = h_a; a.N = NA;
        a.W[0] = gws + 0 * 4096; a.W[1] = gws + 3 * 4096; a.W[2] = gws + 1 * 4096; a.W[3] = gws + 4 * 4096;
        a.As[0] = gas + 0 * 64;  a.As[1] = gas + 3 * 64;  a.As[2] = gas + 1 * 64;  a.As[3] = gas + 4 * 64;
        a.XS[0] = xs_zr0; a.XS[1] = xs_zr0; a.XS[2] = xs_zr1; a.XS[3] = xs_zr1;
        a.ALS[0] = als_zr0; a.ALS[1] = als_zr0 + 1; a.ALS[2] = als_zr1; a.ALS[3] = als_zr1 + 1;
        a.WD[0] = gwd + 0 * 4096; a.WD[1] = gwd + 3 * 4096; a.WD[2] = gwd + 2 * 4096; a.WD[3] = gwd + 5 * 4096;
        a.AD[0] = gad + 0 * 64;   a.AD[1] = gad + 3 * 64;   a.AD[2] = gad + 2 * 64;   a.AD[3] = gad + 5 * 64;
        a.ALD[0] = ald_zr0; a.ALD[1] = ald_zr0 + 1; a.ALD[2] = ald_zr2; a.ALD[3] = ald_zr2 + 1;
        gemm_fused<4, 4, 2><<<512, 256, 0, stream>>>(a);
    }
    {
        GemmArgs a{};
        a.H = h_b; a.N = NB;
        a.W[0] = gws + 2 * 4096; a.W[1] = gws + 5 * 4096;
        a.As[0] = gas + 2 * 64;  a.As[1] = gas + 5 * 64;
        a.XS[0] = xs_zr2; a.XS[1] = xs_zr2;
        a.ALS[0] = als_zr2; a.ALS[1] = als_zr2 + 1;
        a.WD[0] = gwd + 1 * 4096; a.WD[1] = gwd + 4 * 4096;
        a.AD[0] = gad + 1 * 64;   a.AD[1] = gad + 4 * 64;
        a.ALD[0] = ald_zr1; a.ALD[1] = ald_zr1 + 1;
        gemm_fused<2, 2, 2><<<128, 256, 0, stream>>>(a);
    }

    // ---- z+r aggregation (A and B in one launch) ----
    {
        ZrArgs P{};
        P.rp = rp; P.cnt = cnt; P.csr = csr;
        P.als0 = (const float2*)als_zr0; P.ald0 = (const float2*)ald_zr0;
        P.als1 = (const float2*)als_zr1; P.ald1 = (const float2*)ald_zr1;
        P.als2 = (const float2*)als_zr2; P.ald2 = (const float2*)ald_zr2;
        P.xs0 = (const uint4*)xs_zr0; P.xs1 = (const uint4*)xs_zr1; P.xs2 = (const uint4*)xs_zr2;
        P.dzrA = dzrA; P.dzrB = dzrB;
        P.hA = h_a; P.hB = h_b;
        P.zA = z_a; P.rhA = rh_a; P.zB = z_b; P.rhB = rh_b;
        aggregate_zr_k<<<(NA + NB) / 4, 256, 0, stream>>>(P);
    }

    // ---- n GEMMs (input rh) ----
    {
        GemmArgs a{};
        a.H = rh_a; a.N = NA;
        a.W[0] = gws + 6 * 4096; a.W[1] = gws + 7 * 4096;
        a.As[0] = gas + 6 * 64;  a.As[1] = gas + 7 * 64;
        a.XS[0] = xs_n0; a.XS[1] = xs_n1;
        a.ALS[0] = als_n0; a.ALS[1] = als_n1;
        a.WD[0] = gwd + 6 * 4096; a.WD[1] = gwd + 8 * 4096;
        a.AD[0] = gad + 6 * 64;   a.AD[1] = gad + 8 * 64;
        a.ALD[0] = ald_n0; a.ALD[1] = ald_n2;
        gemm_fused<2, 2, 1><<<512, 256, 0, stream>>>(a);
    }
    {
        GemmArgs a{};
        a.H = rh_b; a.N = NB;
        a.W[0] = gws + 8 * 4096;
        a.As[0] = gas + 8 * 64;
        a.XS[0] = xs_n2;
        a.ALS[0] = als_n2;
        a.WD[0] = gwd + 7 * 4096;
        a.AD[0] = gad + 7 * 64;
        a.ALD[0] = ald_n1;
        gemm_fused<1, 1, 1><<<128, 256, 0, stream>>>(a);
    }

    // ---- n aggregation + GRU combine (A and B in one launch) ----
    {
        NArgs P{};
        P.rp = rp; P.cnt = cnt; P.csr = csr;
        P.als0 = als_n0; P.ald0 = ald_n0;
        P.als1 = als_n1; P.ald1 = ald_n1;
        P.als2 = als_n2; P.ald2 = ald_n2;
        P.xs0 = (const uint2*)xs_n0; P.xs1 = (const uint2*)xs_n1; P.xs2 = (const uint2*)xs_n2;
        P.dnA = dnA; P.dnB = dnB;
        P.hA = h_a; P.hB = h_b; P.zA = z_a; P.zB = z_b;
        P.outA = out; P.outB = out + (size_t)NA * 64;
        aggregate_n_k<<<(NA + NB) / 4, 256, 0, stream>>>(P);
    }
}

// Round 6
// 462.968 us; speedup vs baseline: 3.3698x; 1.3225x over previous
//
#include <hip/hip_runtime.h>
#include <hip/hip_bf16.h>
#include <cstddef>
#include <cstdint>

#define NA 50000
#define NB 10000
#define D_IN 32
#define D_OUT 64
#define EA2A 800000
#define EA2B 400000
#define EB2A 400000
#define NCAT (NA + NB + NA)
#define ETOT (EA2A + EA2B + EB2A)

typedef unsigned int u32;
typedef unsigned short u16;
typedef __attribute__((ext_vector_type(8))) short short8_t;
typedef __attribute__((ext_vector_type(4))) float f32x4;

// ---------------- helpers ----------------
__device__ __forceinline__ u32 bf16r(float x) {          // round-to-nearest-even bf16 bits
    u32 u = __float_as_uint(x);
    u += 0x7fffu + ((u >> 16) & 1u);
    return u >> 16;
}
__device__ __forceinline__ float ubf(u32 bits) { return __uint_as_float(bits); }
__device__ __forceinline__ float sigm(float x) { return 1.f / (1.f + __expf(-x)); }
__device__ __forceinline__ u32 cvtpk(float lo, float hi) {   // bf16(lo) | bf16(hi)<<16
    u32 r;
    asm("v_cvt_pk_bf16_f32 %0, %1, %2" : "=v"(r) : "v"(lo), "v"(hi));
    return r;
}

template <int CTRL, int RM>
__device__ __forceinline__ float dppf(float v) {
    return __int_as_float(__builtin_amdgcn_update_dpp(0, __float_as_int(v), CTRL, RM, 0xf, true));
}
__device__ __forceinline__ float wsum64(float v) {
    v += dppf<0x111, 0xf>(v);
    v += dppf<0x112, 0xf>(v);
    v += dppf<0x114, 0xf>(v);
    v += dppf<0x118, 0xf>(v);
    v += dppf<0x142, 0xa>(v);
    v += dppf<0x143, 0xc>(v);
    return __int_as_float(__builtin_amdgcn_readlane(__float_as_int(v), 63));
}
// max clamped at >= 0 (bound_ctrl injects 0) — safe: m only needs >= true max
__device__ __forceinline__ float wmax64(float v) {
    v = fmaxf(v, dppf<0x111, 0xf>(v));
    v = fmaxf(v, dppf<0x112, 0xf>(v));
    v = fmaxf(v, dppf<0x114, 0xf>(v));
    v = fmaxf(v, dppf<0x118, 0xf>(v));
    v = fmaxf(v, dppf<0x142, 0xa>(v));
    v = fmaxf(v, dppf<0x143, 0xc>(v));
    return __int_as_float(__builtin_amdgcn_readlane(__float_as_int(v), 63));
}

// ---------------- MFMA staging GEMM ----------------
// xs[m] = bf16(H @ W[m]) for NMAT matrices (packed u32 zr if NMAT==2, u16 if 1),
// plus up to 8 scalar matvec streams SOUT[c][row*sstride] = H[row] . (SW[c] @ SA[c])
// computed as one extra 16x16 MFMA tile.
struct MmArgs {
    const float* H; int ntiles;
    const float* W0; const float* W1;
    void* XS;
    const float* SW[8]; const float* SA[8]; float* SOUT[8];
    int sstride; int nsc;
};

template <int NMAT>
__global__ void __launch_bounds__(256) gemm_mfma(MmArgs a)
{
    __shared__ float wvec[8][64];
    __shared__ short8_t bfr[NMAT * 8 + 2][64];
    int t = threadIdx.x;
    // scalar-stream vectors: wvec[c][k] = sum_d SW[c][k][d] * SA[c][d]
    for (int idx = t; idx < a.nsc * 64; idx += 256) {
        int c = idx >> 6, k = idx & 63;
        const float* w = a.SW[c] + k * 64;
        const float* av = a.SA[c];
        float s = 0.f;
#pragma unroll 16
        for (int e = 0; e < 64; ++e) s = fmaf(w[e], av[e], s);
        wvec[c][k] = s;
    }
    __syncthreads();
    // W B-fragments: frag fid = m*8 + tn*2 + q; lane l holds B[k=32q+(l>>4)*8+e][d=16tn+(l&15)]
    for (int idx = t; idx < NMAT * 8 * 64; idx += 256) {
        int fid = idx >> 6, l = idx & 63;
        int m = fid >> 3, r3 = fid & 7, tn = r3 >> 1, q = r3 & 1;
        const float* W = (NMAT == 2 && m == 1) ? a.W1 : a.W0;
        int kbase = 32 * q + ((l >> 4) << 3);
        int d = 16 * tn + (l & 15);
        short8_t v;
#pragma unroll
        for (int e = 0; e < 8; ++e) v[e] = (short)bf16r(W[(size_t)(kbase + e) * 64 + d]);
        bfr[fid][l] = v;
    }
    // scalar B-fragments (cols = streams)
    for (int idx = t; idx < 128; idx += 256) {
        int q = idx >> 6, l = idx & 63;
        int c = l & 15;
        int kbase = 32 * q + ((l >> 4) << 3);
        short8_t v;
#pragma unroll
        for (int e = 0; e < 8; ++e) v[e] = (c < a.nsc) ? (short)bf16r(wvec[c][kbase + e]) : (short)0;
        bfr[NMAT * 8 + q][l] = v;
    }
    __syncthreads();
    int lane = t & 63, wid = t >> 6;
    short8_t bw[NMAT][4][2], bs0, bs1;
#pragma unroll
    for (int m = 0; m < NMAT; ++m)
#pragma unroll
        for (int tn = 0; tn < 4; ++tn)
#pragma unroll
            for (int q = 0; q < 2; ++q) bw[m][tn][q] = bfr[m * 8 + tn * 2 + q][lane];
    bs0 = bfr[NMAT * 8][lane];
    bs1 = bfr[NMAT * 8 + 1][lane];

    int rl = lane & 15, kg = lane >> 4;
    f32x4 zero = {0.f, 0.f, 0.f, 0.f};
    for (int tile = blockIdx.x * 4 + wid; tile < a.ntiles; tile += gridDim.x * 4) {
        const float4* hp = (const float4*)(a.H + (size_t)(tile * 16 + rl) * 64) + kg * 2;
        float4 a0 = hp[0], a1 = hp[1];   // k = kg*8 .. kg*8+7
        float4 b0 = hp[8], b1 = hp[9];   // k = 32 + kg*8 ..
        union { short8_t s; u32 w[4]; } A0, A1;
        A0.w[0] = cvtpk(a0.x, a0.y); A0.w[1] = cvtpk(a0.z, a0.w);
        A0.w[2] = cvtpk(a1.x, a1.y); A0.w[3] = cvtpk(a1.z, a1.w);
        A1.w[0] = cvtpk(b0.x, b0.y); A1.w[1] = cvtpk(b0.z, b0.w);
        A1.w[2] = cvtpk(b1.x, b1.y); A1.w[3] = cvtpk(b1.z, b1.w);

        f32x4 acc[NMAT][4];
#pragma unroll
        for (int m = 0; m < NMAT; ++m)
#pragma unroll
            for (int tn = 0; tn < 4; ++tn) {
                f32x4 c0 = __builtin_amdgcn_mfma_f32_16x16x32_bf16(A0.s, bw[m][tn][0], zero, 0, 0, 0);
                acc[m][tn] = __builtin_amdgcn_mfma_f32_16x16x32_bf16(A1.s, bw[m][tn][1], c0, 0, 0, 0);
            }
        f32x4 accs = __builtin_amdgcn_mfma_f32_16x16x32_bf16(A0.s, bs0, zero, 0, 0, 0);
        accs = __builtin_amdgcn_mfma_f32_16x16x32_bf16(A1.s, bs1, accs, 0, 0, 0);

        int rbase = tile * 16 + kg * 4;   // C rows: (lane>>4)*4 + j
        if (NMAT == 2) {
            u32* xo = (u32*)a.XS;
#pragma unroll
            for (int tn = 0; tn < 4; ++tn) {
                int d = tn * 16 + rl;
#pragma unroll
                for (int j = 0; j < 4; ++j)
                    xo[(size_t)(rbase + j) * 64 + d] = cvtpk(acc[0][tn][j], acc[1][tn][j]);
            }
        } else {
            u16* xo = (u16*)a.XS;
#pragma unroll
            for (int tn = 0; tn < 4; ++tn) {
                int d = tn * 16 + rl;
#pragma unroll
                for (int j = 0; j < 4; ++j)
                    xo[(size_t)(rbase + j) * 64 + d] = (u16)bf16r(acc[0][tn][j]);
            }
        }
        if (rl < a.nsc) {
            float* so = a.SOUT[rl];
#pragma unroll
            for (int j = 0; j < 4; ++j) so[(size_t)(rbase + j) * a.sstride] = accs[j];
        }
    }
}

// ---------------- dense precompute: d*(node,dim) = x @ Wx[g] + bx + sum(gat_b) ----
__global__ void __launch_bounds__(256) gemm_x_k(
    const float* __restrict__ xA, const float* __restrict__ xB,
    const float* __restrict__ Wx, const float* __restrict__ bx, const float* __restrict__ gb,
    u32* __restrict__ dzrA, u32* __restrict__ dzrB,
    u16* __restrict__ dnA, u16* __restrict__ dnB)
{
    __shared__ float Wsh[3 * 2048];
    __shared__ float cb[3 * 64];
    int t = threadIdx.x;
    int blk = blockIdx.x;
    bool isA = blk < (NA / 8);
    int ty = isA ? 0 : 1;
#pragma unroll
    for (int g = 0; g < 3; ++g) {
        const float4* s = (const float4*)(Wx + (size_t)(g * 2 + ty) * 2048);
        float4* d = (float4*)&Wsh[g * 2048];
        for (int i = t; i < 512; i += 256) d[i] = s[i];
    }
    if (t < 192) {
        int g = t >> 6, d = t & 63;
        float c = bx[(g * 2 + ty) * 64 + d];
        if (isA) c += gb[(g * 3 + 0) * 64 + d] + gb[(g * 3 + 2) * 64 + d];
        else     c += gb[(g * 3 + 1) * 64 + d];
        cb[t] = c;
    }
    __syncthreads();
    int lane = t & 63, wid = t >> 6;
    const float* X = isA ? xA : xB;
    int N = isA ? NA : NB;
    int rbase = (isA ? blk : blk - NA / 8) * 8 + wid * 2;
    float cz = cb[lane], cr = cb[64 + lane], cn = cb[128 + lane];
#pragma unroll
    for (int rr = 0; rr < 2; ++rr) {
        int r = rbase + rr;
        if (r >= N) break;
        float xv = (lane < 32) ? X[(size_t)r * 32 + lane] : 0.f;
        float az = cz, ar = cr, an = cn;
#pragma unroll
        for (int k = 0; k < 32; ++k) {
            float xk = __shfl(xv, k, 64);
            az = fmaf(xk, Wsh[k * 64 + lane], az);
            ar = fmaf(xk, Wsh[2048 + k * 64 + lane], ar);
            an = fmaf(xk, Wsh[4096 + k * 64 + lane], an);
        }
        u32 zr = bf16r(az) | (bf16r(ar) << 16);
        u16 nn = (u16)bf16r(an);
        if (isA) { dzrA[(size_t)r * 64 + lane] = zr; dnA[(size_t)r * 64 + lane] = nn; }
        else     { dzrB[(size_t)r * 64 + lane] = zr; dnB[(size_t)r * 64 + lane] = nn; }
    }
}

// ---------------- unified CSR build ----------------
__global__ void hist_k(const int* __restrict__ d0, const int* __restrict__ d1,
                       const int* __restrict__ d2, int* __restrict__ cnt)
{
    for (int e = blockIdx.x * blockDim.x + threadIdx.x; e < ETOT; e += gridDim.x * blockDim.x) {
        int g;
        if (e < EA2A) g = d0[e];
        else if (e < EA2A + EA2B) g = NA + d1[e - EA2A];
        else g = NA + NB + d2[e - EA2A - EA2B];
        atomicAdd(&cnt[g], 1);
    }
}

__global__ void scan_partial(const int* __restrict__ cnt, int* __restrict__ bsum, int N)
{
    __shared__ int sd[256];
    int t = threadIdx.x;
    int i = blockIdx.x * 256 + t;
    sd[t] = (i < N) ? cnt[i] : 0;
    __syncthreads();
    for (int off = 128; off; off >>= 1) {
        if (t < off) sd[t] += sd[t + off];
        __syncthreads();
    }
    if (t == 0) bsum[blockIdx.x] = sd[0];
}

__global__ void scan_tops(int* bsum, int nb)
{
    if (threadIdx.x == 0 && blockIdx.x == 0) {
        int run = 0;
        for (int b = 0; b < nb; ++b) { int v = bsum[b]; bsum[b] = run; run += v; }
    }
}

__global__ void scan_final(const int* __restrict__ cnt, const int* __restrict__ bsum,
                           int* __restrict__ rowptr, int N)
{
    __shared__ int sd[256];
    int t = threadIdx.x;
    int i = blockIdx.x * 256 + t;
    int v = (i < N) ? cnt[i] : 0;
    sd[t] = v;
    __syncthreads();
    for (int off = 1; off < 256; off <<= 1) {
        int add = (t >= off) ? sd[t - off] : 0;
        __syncthreads();
        sd[t] += add;
        __syncthreads();
    }
    if (i < N) rowptr[i] = bsum[blockIdx.x] + sd[t] - v;
}

__global__ void fill_k(const int* __restrict__ s0, const int* __restrict__ d0,
                       const int* __restrict__ s1, const int* __restrict__ d1,
                       const int* __restrict__ s2, const int* __restrict__ d2,
                       const int* __restrict__ rp, int* __restrict__ fp, u16* __restrict__ csr)
{
    for (int e = blockIdx.x * blockDim.x + threadIdx.x; e < ETOT; e += gridDim.x * blockDim.x) {
        int g, s;
        if (e < EA2A) { g = d0[e]; s = s0[e]; }
        else if (e < EA2A + EA2B) { int k = e - EA2A; g = NA + d1[k]; s = s1[k]; }
        else { int k = e - EA2A - EA2B; g = NA + NB + d2[k]; s = s2[k]; }
        int p = atomicAdd(&fp[g], 1);
        csr[rp[g] + p] = (u16)s;
    }
}

// ---------------- GAT per-edge-type contributions ----------------
__device__ __forceinline__ void zr_fma(float az[4], float ar[4], uint4 v, float pz, float pr) {
    az[0] = fmaf(pz, ubf(v.x << 16), az[0]); ar[0] = fmaf(pr, ubf(v.x & 0xffff0000u), ar[0]);
    az[1] = fmaf(pz, ubf(v.y << 16), az[1]); ar[1] = fmaf(pr, ubf(v.y & 0xffff0000u), ar[1]);
    az[2] = fmaf(pz, ubf(v.z << 16), az[2]); ar[2] = fmaf(pr, ubf(v.z & 0xffff0000u), ar[2]);
    az[3] = fmaf(pz, ubf(v.w << 16), az[3]); ar[3] = fmaf(pr, ubf(v.w & 0xffff0000u), ar[3]);
}

__device__ __forceinline__ void gat_zr_et(
    int gnode, int inode, int lane, int sub, int grp,
    const int* __restrict__ rp, const int* __restrict__ cnt, const u16* __restrict__ csr,
    const float2* __restrict__ als, const float2* __restrict__ ald,
    const uint4* __restrict__ xs,
    float oz[4], float orr[4])
{
    int deg = cnt[gnode];
    if (deg <= 0) return;
    int beg = rp[gnode];
    float2 ad = ald[inode];
    float mz = 0.f, mr = 0.f, sz = 0.f, sr = 0.f;
    float az[4] = {0.f, 0.f, 0.f, 0.f}, ar[4] = {0.f, 0.f, 0.f, 0.f};
    for (int base = 0; base < deg; base += 64) {
        int j = base + lane;
        int sj = 0; float ez = -1e30f, er = -1e30f;
        if (j < deg) {
            sj = csr[beg + j];
            float2 al = als[sj];
            float tz = al.x + ad.x; ez = tz > 0.f ? tz : 0.2f * tz;
            float tr = al.y + ad.y; er = tr > 0.f ? tr : 0.2f * tr;
        }
        float cmz = wmax64(ez), cmr = wmax64(er);
        if (base == 0) { mz = cmz; mr = cmr; }
        else {
            if (cmz > mz) { float s = __expf(mz - cmz);
                az[0] *= s; az[1] *= s; az[2] *= s; az[3] *= s; sz *= s; mz = cmz; }
            if (cmr > mr) { float s = __expf(mr - cmr);
                ar[0] *= s; ar[1] *= s; ar[2] *= s; ar[3] *= s; sr *= s; mr = cmr; }
        }
        float pz = (j < deg) ? __expf(ez - mz) : 0.f;
        float pr = (j < deg) ? __expf(er - mr) : 0.f;
        sz += wsum64(pz);
        sr += wsum64(pr);
        u32 pk = (u32)sj | (bf16r(pz) << 16);   // invalid lanes: pk=0 -> contributes 0
        int c = deg - base; if (c > 64) c = 64;
        int b = 0;
        for (; b + 16 <= c; b += 16) {
            u32 k0 = (u32)__shfl((int)pk, b + grp, 64);
            u32 k1 = (u32)__shfl((int)pk, b + 4 + grp, 64);
            u32 k2 = (u32)__shfl((int)pk, b + 8 + grp, 64);
            u32 k3 = (u32)__shfl((int)pk, b + 12 + grp, 64);
            float q0 = __shfl(pr, b + grp, 64);
            float q1 = __shfl(pr, b + 4 + grp, 64);
            float q2 = __shfl(pr, b + 8 + grp, 64);
            float q3 = __shfl(pr, b + 12 + grp, 64);
            uint4 v0 = xs[(size_t)(k0 & 0xffffu) * 16 + sub];
            uint4 v1 = xs[(size_t)(k1 & 0xffffu) * 16 + sub];
            uint4 v2 = xs[(size_t)(k2 & 0xffffu) * 16 + sub];
            uint4 v3 = xs[(size_t)(k3 & 0xffffu) * 16 + sub];
            zr_fma(az, ar, v0, ubf(k0 & 0xffff0000u), q0);
            zr_fma(az, ar, v1, ubf(k1 & 0xffff0000u), q1);
            zr_fma(az, ar, v2, ubf(k2 & 0xffff0000u), q2);
            zr_fma(az, ar, v3, ubf(k3 & 0xffff0000u), q3);
        }
        for (; b < c; b += 4) {
            u32 k0 = (u32)__shfl((int)pk, b + grp, 64);
            float q0 = __shfl(pr, b + grp, 64);
            uint4 v0 = xs[(size_t)(k0 & 0xffffu) * 16 + sub];
            zr_fma(az, ar, v0, ubf(k0 & 0xffff0000u), q0);
        }
    }
    float rz = 1.f / (sz + 1e-16f), rr = 1.f / (sr + 1e-16f);
    oz[0] = fmaf(az[0], rz, oz[0]); orr[0] = fmaf(ar[0], rr, orr[0]);
    oz[1] = fmaf(az[1], rz, oz[1]); orr[1] = fmaf(ar[1], rr, orr[1]);
    oz[2] = fmaf(az[2], rz, oz[2]); orr[2] = fmaf(ar[2], rr, orr[2]);
    oz[3] = fmaf(az[3], rz, oz[3]); orr[3] = fmaf(ar[3], rr, orr[3]);
}

__device__ __forceinline__ void n_fma(float a[4], uint2 v, float p) {
    a[0] = fmaf(p, ubf(v.x << 16), a[0]);
    a[1] = fmaf(p, ubf(v.x & 0xffff0000u), a[1]);
    a[2] = fmaf(p, ubf(v.y << 16), a[2]);
    a[3] = fmaf(p, ubf(v.y & 0xffff0000u), a[3]);
}

__device__ __forceinline__ void gat_n_et(
    int gnode, int inode, int lane, int sub, int grp,
    const int* __restrict__ rp, const int* __restrict__ cnt, const u16* __restrict__ csr,
    const float* __restrict__ als, const float* __restrict__ ald,
    const uint2* __restrict__ xs,
    float oa[4])
{
    int deg = cnt[gnode];
    if (deg <= 0) return;
    int beg = rp[gnode];
    float ad = ald[inode];
    float m = 0.f, ss = 0.f;
    float ac[4] = {0.f, 0.f, 0.f, 0.f};
    for (int base = 0; base < deg; base += 64) {
        int j = base + lane;
        int sj = 0; float e = -1e30f;
        if (j < deg) {
            sj = csr[beg + j];
            float tv = als[sj] + ad;
            e = tv > 0.f ? tv : 0.2f * tv;
        }
        float cm = wmax64(e);
        if (base == 0) m = cm;
        else if (cm > m) {
            float s = __expf(m - cm);
            ac[0] *= s; ac[1] *= s; ac[2] *= s; ac[3] *= s; ss *= s; m = cm;
        }
        float p = (j < deg) ? __expf(e - m) : 0.f;
        ss += wsum64(p);
        u32 pk = (u32)sj | (bf16r(p) << 16);
        int c = deg - base; if (c > 64) c = 64;
        int b = 0;
        for (; b + 16 <= c; b += 16) {
            u32 k0 = (u32)__shfl((int)pk, b + grp, 64);
            u32 k1 = (u32)__shfl((int)pk, b + 4 + grp, 64);
            u32 k2 = (u32)__shfl((int)pk, b + 8 + grp, 64);
            u32 k3 = (u32)__shfl((int)pk, b + 12 + grp, 64);
            uint2 v0 = xs[(size_t)(k0 & 0xffffu) * 16 + sub];
            uint2 v1 = xs[(size_t)(k1 & 0xffffu) * 16 + sub];
            uint2 v2 = xs[(size_t)(k2 & 0xffffu) * 16 + sub];
            uint2 v3 = xs[(size_t)(k3 & 0xffffu) * 16 + sub];
            n_fma(ac, v0, ubf(k0 & 0xffff0000u));
            n_fma(ac, v1, ubf(k1 & 0xffff0000u));
            n_fma(ac, v2, ubf(k2 & 0xffff0000u));
            n_fma(ac, v3, ubf(k3 & 0xffff0000u));
        }
        for (; b < c; b += 4) {
            u32 k0 = (u32)__shfl((int)pk, b + grp, 64);
            uint2 v0 = xs[(size_t)(k0 & 0xffffu) * 16 + sub];
            n_fma(ac, v0, ubf(k0 & 0xffff0000u));
        }
    }
    float rs = 1.f / (ss + 1e-16f);
    oa[0] = fmaf(ac[0], rs, oa[0]);
    oa[1] = fmaf(ac[1], rs, oa[1]);
    oa[2] = fmaf(ac[2], rs, oa[2]);
    oa[3] = fmaf(ac[3], rs, oa[3]);
}

// ---------------- aggregate kernels (A and B merged) ----------------
struct ZrArgs {
    const int *rp, *cnt;
    const u16 *csr;
    const float2 *als0, *ald0, *als1, *ald1, *als2, *ald2;
    const uint4 *xs0, *xs1, *xs2;
    const u32 *dzrA, *dzrB;
    const float *hA, *hB;
    float *zA, *rhA, *zB, *rhB;
};

__global__ void __launch_bounds__(256) aggregate_zr_k(ZrArgs P)
{
    int t = threadIdx.x, lane = t & 63, wid = t >> 6;
    int sub = lane & 15, grp = lane >> 4;
    float oz[4] = {0.f, 0.f, 0.f, 0.f}, orr[4] = {0.f, 0.f, 0.f, 0.f};
    int blk = blockIdx.x;
    const u32* dzr; const float* Hp; float *Zp, *RHp;
    if (blk < NA / 4) {
        int i = blk * 4 + wid;
        gat_zr_et(i, i, lane, sub, grp, P.rp, P.cnt, P.csr, P.als0, P.ald0, P.xs0, oz, orr);
        gat_zr_et(NA + NB + i, i, lane, sub, grp, P.rp, P.cnt, P.csr, P.als2, P.ald2, P.xs2, oz, orr);
        dzr = P.dzrA + (size_t)i * 64; Hp = P.hA + (size_t)i * 64;
        Zp = P.zA + (size_t)i * 64; RHp = P.rhA + (size_t)i * 64;
    } else {
        int i = (blk - NA / 4) * 4 + wid;
        gat_zr_et(NA + i, i, lane, sub, grp, P.rp, P.cnt, P.csr, P.als1, P.ald1, P.xs1, oz, orr);
        dzr = P.dzrB + (size_t)i * 64; Hp = P.hB + (size_t)i * 64;
        Zp = P.zB + (size_t)i * 64; RHp = P.rhB + (size_t)i * 64;
    }
#pragma unroll
    for (int q = 0; q < 4; ++q) {
        oz[q] += __shfl_xor(oz[q], 16, 64); oz[q] += __shfl_xor(oz[q], 32, 64);
        orr[q] += __shfl_xor(orr[q], 16, 64); orr[q] += __shfl_xor(orr[q], 32, 64);
    }
    if (grp == 0) {
        uint4 d = *(const uint4*)(dzr + sub * 4);
        float4 h = *(const float4*)(Hp + sub * 4);
        float z0 = sigm(oz[0] + ubf(d.x << 16)), r0 = sigm(orr[0] + ubf(d.x & 0xffff0000u)) * h.x;
        float z1 = sigm(oz[1] + ubf(d.y << 16)), r1 = sigm(orr[1] + ubf(d.y & 0xffff0000u)) * h.y;
        float z2 = sigm(oz[2] + ubf(d.z << 16)), r2 = sigm(orr[2] + ubf(d.z & 0xffff0000u)) * h.z;
        float z3 = sigm(oz[3] + ubf(d.w << 16)), r3 = sigm(orr[3] + ubf(d.w & 0xffff0000u)) * h.w;
        *(float4*)(Zp + sub * 4) = make_float4(z0, z1, z2, z3);
        *(float4*)(RHp + sub * 4) = make_float4(r0, r1, r2, r3);
    }
}

struct NArgs {
    const int *rp, *cnt;
    const u16 *csr;
    const float *als0, *ald0, *als1, *ald1, *als2, *ald2;
    const uint2 *xs0, *xs1, *xs2;
    const u16 *dnA, *dnB;
    const float *hA, *hB, *zA, *zB;
    float *outA, *outB;
};

__global__ void __launch_bounds__(256) aggregate_n_k(NArgs P)
{
    int t = threadIdx.x, lane = t & 63, wid = t >> 6;
    int sub = lane & 15, grp = lane >> 4;
    float oa[4] = {0.f, 0.f, 0.f, 0.f};
    int blk = blockIdx.x;
    const u16* dn; const float *Hp, *Zp; float* Op;
    if (blk < NA / 4) {
        int i = blk * 4 + wid;
        gat_n_et(i, i, lane, sub, grp, P.rp, P.cnt, P.csr, P.als0, P.ald0, P.xs0, oa);
        gat_n_et(NA + NB + i, i, lane, sub, grp, P.rp, P.cnt, P.csr, P.als2, P.ald2, P.xs2, oa);
        dn = P.dnA + (size_t)i * 64; Hp = P.hA + (size_t)i * 64;
        Zp = P.zA + (size_t)i * 64; Op = P.outA + (size_t)i * 64;
    } else {
        int i = (blk - NA / 4) * 4 + wid;
        gat_n_et(NA + i, i, lane, sub, grp, P.rp, P.cnt, P.csr, P.als1, P.ald1, P.xs1, oa);
        dn = P.dnB + (size_t)i * 64; Hp = P.hB + (size_t)i * 64;
        Zp = P.zB + (size_t)i * 64; Op = P.outB + (size_t)i * 64;
    }
#pragma unroll
    for (int q = 0; q < 4; ++q) {
        oa[q] += __shfl_xor(oa[q], 16, 64); oa[q] += __shfl_xor(oa[q], 32, 64);
    }
    if (grp == 0) {
        uint2 d = *(const uint2*)(dn + sub * 4);
        float4 h = *(const float4*)(Hp + sub * 4);
        float4 zv = *(const float4*)(Zp + sub * 4);
        float pre[4];
        pre[0] = oa[0] + ubf(d.x << 16);
        pre[1] = oa[1] + ubf(d.x & 0xffff0000u);
        pre[2] = oa[2] + ubf(d.y << 16);
        pre[3] = oa[3] + ubf(d.y & 0xffff0000u);
        float o[4];
        float hh[4] = {h.x, h.y, h.z, h.w};
        float zz[4] = {zv.x, zv.y, zv.z, zv.w};
#pragma unroll
        for (int q = 0; q < 4; ++q) {
            float x2 = fminf(fmaxf(pre[q] * 2.f, -30.f), 30.f);
            float ex = __expf(x2);
            float nv = (ex - 1.f) / (ex + 1.f);
            o[q] = (1.f - zz[q]) * nv + zz[q] * hh[q];
        }
        *(float4*)(Op + sub * 4) = make_float4(o[0], o[1], o[2], o[3]);
    }
}

// ---------------- host side ----------------
extern "C" void kernel_launch(void* const* d_in, const int* in_sizes, int n_in,
                              void* d_out, int out_size, void* d_ws, size_t ws_size,
                              hipStream_t stream)
{
    (void)in_sizes; (void)n_in; (void)out_size; (void)ws_size;
    const float* x_a = (const float*)d_in[0];
    const float* x_b = (const float*)d_in[1];
    const float* h_a = (const float*)d_in[2];
    const float* h_b = (const float*)d_in[3];
    const float* Wx  = (const float*)d_in[4];
    const float* bx  = (const float*)d_in[5];
    const float* gws = (const float*)d_in[6];
    const float* gwd = (const float*)d_in[7];
    const float* gas = (const float*)d_in[8];
    const float* gad = (const float*)d_in[9];
    const float* gb  = (const float*)d_in[10];
    const int* ea2a_s = (const int*)d_in[11];
    const int* ea2a_d = (const int*)d_in[12];
    const int* ea2b_s = (const int*)d_in[13];
    const int* ea2b_d = (const int*)d_in[14];
    const int* eb2a_s = (const int*)d_in[15];
    const int* eb2a_d = (const int*)d_in[16];
    float* out = (float*)d_out;

    char* w = (char*)d_ws;
    auto alloc = [&](size_t bytes) -> char* {
        char* p = w;
        w += (bytes + 255) & ~(size_t)255;
        return p;
    };
    // xs block: zr phase u32[N*64]; n phase aliases low half as u16[N*64]
    char* xsblk = alloc((size_t)(NA + NA + NB) * 64 * 4);
    u32* xs_zr0 = (u32*)xsblk;
    u32* xs_zr1 = (u32*)(xsblk + (size_t)NA * 64 * 4);
    u32* xs_zr2 = (u32*)(xsblk + (size_t)(NA + NA) * 64 * 4);
    u16* xs_n0 = (u16*)xsblk;
    u16* xs_n1 = (u16*)(xsblk + (size_t)NA * 64 * 2);
    u16* xs_n2 = (u16*)(xsblk + (size_t)(NA + NA) * 64 * 2);
    // al block: zr float2 per node; n aliases as float per node
    char* alblk = alloc((size_t)(4 * NA + 2 * NB) * 2 * 4);
    float* als_zr0 = (float*)alblk;
    float* als_zr1 = als_zr0 + (size_t)NA * 2;
    float* als_zr2 = als_zr1 + (size_t)NA * 2;
    float* ald_zr0 = als_zr2 + (size_t)NB * 2;
    float* ald_zr1 = ald_zr0 + (size_t)NA * 2;
    float* ald_zr2 = ald_zr1 + (size_t)NB * 2;
    float* als_n0 = (float*)alblk;
    float* als_n1 = als_n0 + NA;
    float* als_n2 = als_n1 + NA;
    float* ald_n0 = als_n2 + NB;
    float* ald_n1 = ald_n0 + NA;
    float* ald_n2 = ald_n1 + NB;
    float* zbuf  = (float*)alloc((size_t)(NA + NB) * 64 * 4);
    float* rhbuf = (float*)alloc((size_t)(NA + NB) * 64 * 4);
    u32* dzrA = (u32*)alloc((size_t)NA * 64 * 4);
    u32* dzrB = (u32*)alloc((size_t)NB * 64 * 4);
    u16* dnA = (u16*)alloc((size_t)NA * 64 * 2);
    u16* dnB = (u16*)alloc((size_t)NB * 64 * 2);
    char* zero_begin = w;
    int* cnt = (int*)alloc((size_t)NCAT * 4);
    int* fp  = (int*)alloc((size_t)NCAT * 4);
    char* zero_end = w;
    int* rp  = (int*)alloc((size_t)NCAT * 4);
    u16* csr = (u16*)alloc((size_t)ETOT * 2);
    int* bsum = (int*)alloc(512 * 4);

    const int nbC = (NCAT + 255) / 256;

    // ---- CSR build (unified) ----
    (void)hipMemsetAsync(zero_begin, 0, (size_t)(zero_end - zero_begin), stream);
    hist_k<<<2048, 256, 0, stream>>>(ea2a_d, ea2b_d, eb2a_d, cnt);
    scan_partial<<<nbC, 256, 0, stream>>>(cnt, bsum, NCAT);
    scan_tops<<<1, 64, 0, stream>>>(bsum, nbC);
    scan_final<<<nbC, 256, 0, stream>>>(cnt, bsum, rp, NCAT);
    fill_k<<<2048, 256, 0, stream>>>(ea2a_s, ea2a_d, ea2b_s, ea2b_d, eb2a_s, eb2a_d, rp, fp, csr);

    // ---- dense precompute (all 3 gates, both node types) ----
    gemm_x_k<<<(NA + NB) / 8, 256, 0, stream>>>(x_a, x_b, Wx, bx, gb, dzrA, dzrB, dnA, dnB);

    float* rh_a = rhbuf;
    float* rh_b = rhbuf + (size_t)NA * 64;
    float* z_a = zbuf;
    float* z_b = zbuf + (size_t)NA * 64;

    // ---- z+r MFMA GEMMs ----
    {   // pair (z,a2a)+(r,a2a) on h_a, + all 8 h_a-derived scalar streams
        MmArgs a{};
        a.H = h_a; a.ntiles = NA / 16;
        a.W0 = gws + 0 * 4096; a.W1 = gws + 3 * 4096;
        a.XS = xs_zr0;
        a.SW[0] = gws + 0 * 4096; a.SA[0] = gas + 0 * 64; a.SOUT[0] = als_zr0;
        a.SW[1] = gws + 3 * 4096; a.SA[1] = gas + 3 * 64; a.SOUT[1] = als_zr0 + 1;
        a.SW[2] = gws + 1 * 4096; a.SA[2] = gas + 1 * 64; a.SOUT[2] = als_zr1;
        a.SW[3] = gws + 4 * 4096; a.SA[3] = gas + 4 * 64; a.SOUT[3] = als_zr1 + 1;
        a.SW[4] = gwd + 0 * 4096; a.SA[4] = gad + 0 * 64; a.SOUT[4] = ald_zr0;
        a.SW[5] = gwd + 3 * 4096; a.SA[5] = gad + 3 * 64; a.SOUT[5] = ald_zr0 + 1;
        a.SW[6] = gwd + 2 * 4096; a.SA[6] = gad + 2 * 64; a.SOUT[6] = ald_zr2;
        a.SW[7] = gwd + 5 * 4096; a.SA[7] = gad + 5 * 64; a.SOUT[7] = ald_zr2 + 1;
        a.sstride = 2; a.nsc = 8;
        gemm_mfma<2><<<320, 256, 0, stream>>>(a);
    }
    {   // pair (z,a2b)+(r,a2b) on h_a
        MmArgs a{};
        a.H = h_a; a.ntiles = NA / 16;
        a.W0 = gws + 1 * 4096; a.W1 = gws + 4 * 4096;
        a.XS = xs_zr1;
        a.sstride = 1; a.nsc = 0;
        gemm_mfma<2><<<320, 256, 0, stream>>>(a);
    }
    {   // pair (z,b2a)+(r,b2a) on h_b, + 4 h_b scalar streams
        MmArgs a{};
        a.H = h_b; a.ntiles = NB / 16;
        a.W0 = gws + 2 * 4096; a.W1 = gws + 5 * 4096;
        a.XS = xs_zr2;
        a.SW[0] = gws + 2 * 4096; a.SA[0] = gas + 2 * 64; a.SOUT[0] = als_zr2;
        a.SW[1] = gws + 5 * 4096; a.SA[1] = gas + 5 * 64; a.SOUT[1] = als_zr2 + 1;
        a.SW[2] = gwd + 1 * 4096; a.SA[2] = gad + 1 * 64; a.SOUT[2] = ald_zr1;
        a.SW[3] = gwd + 4 * 4096; a.SA[3] = gad + 4 * 64; a.SOUT[3] = ald_zr1 + 1;
        a.sstride = 2; a.nsc = 4;
        gemm_mfma<2><<<80, 256, 0, stream>>>(a);
    }

    // ---- z+r aggregation ----
    {
        ZrArgs P{};
        P.rp = rp; P.cnt = cnt; P.csr = csr;
        P.als0 = (const float2*)als_zr0; P.ald0 = (const float2*)ald_zr0;
        P.als1 = (const float2*)als_zr1; P.ald1 = (const float2*)ald_zr1;
        P.als2 = (const float2*)als_zr2; P.ald2 = (const float2*)ald_zr2;
        P.xs0 = (const uint4*)xs_zr0; P.xs1 = (const uint4*)xs_zr1; P.xs2 = (const uint4*)xs_zr2;
        P.dzrA = dzrA; P.dzrB = dzrB;
        P.hA = h_a; P.hB = h_b;
        P.zA = z_a; P.rhA = rh_a; P.zB = z_b; P.rhB = rh_b;
        aggregate_zr_k<<<(NA + NB) / 4, 256, 0, stream>>>(P);
    }

    // ---- n MFMA GEMMs (input rh) ----
    {   // (n,a2a) on rh_a, + 4 rh_a scalar streams
        MmArgs a{};
        a.H = rh_a; a.ntiles = NA / 16;
        a.W0 = gws + 6 * 4096; a.W1 = nullptr;
        a.XS = xs_n0;
        a.SW[0] = gws + 6 * 4096; a.SA[0] = gas + 6 * 64; a.SOUT[0] = als_n0;
        a.SW[1] = gws + 7 * 4096; a.SA[1] = gas + 7 * 64; a.SOUT[1] = als_n1;
        a.SW[2] = gwd + 6 * 4096; a.SA[2] = gad + 6 * 64; a.SOUT[2] = ald_n0;
        a.SW[3] = gwd + 8 * 4096; a.SA[3] = gad + 8 * 64; a.SOUT[3] = ald_n2;
        a.sstride = 1; a.nsc = 4;
        gemm_mfma<1><<<320, 256, 0, stream>>>(a);
    }
    {   // (n,a2b) on rh_a
        MmArgs a{};
        a.H = rh_a; a.ntiles = NA / 16;
        a.W0 = gws + 7 * 4096; a.W1 = nullptr;
        a.XS = xs_n1;
        a.sstride = 1; a.nsc = 0;
        gemm_mfma<1><<<320, 256, 0, stream>>>(a);
    }
    {   // (n,b2a) on rh_b, + 2 rh_b scalar streams
        MmArgs a{};
        a.H = rh_b; a.ntiles = NB / 16;
        a.W0 = gws + 8 * 4096; a.W1 = nullptr;
        a.XS = xs_n2;
        a.SW[0] = gws + 8 * 4096; a.SA[0] = gas + 8 * 64; a.SOUT[0] = als_n2;
        a.SW[1] = gwd + 7 * 4096; a.SA[1] = gad + 7 * 64; a.SOUT[1] = ald_n1;
        a.sstride = 1; a.nsc = 2;
        gemm_mfma<1><<<80, 256, 0, stream>>>(a);
    }

    // ---- n aggregation + GRU combine ----
    {
        NArgs P{};
        P.rp = rp; P.cnt = cnt; P.csr = csr;
        P.als0 = als_n0; P.ald0 = ald_n0;
        P.als1 = als_n1; P.ald1 = ald_n1;
        P.als2 = als_n2; P.ald2 = ald_n2;
        P.xs0 = (const uint2*)xs_n0; P.xs1 = (const uint2*)xs_n1; P.xs2 = (const uint2*)xs_n2;
        P.dnA = dnA; P.dnB = dnB;
        P.hA = h_a; P.hB = h_b; P.zA = z_a; P.zB = z_b;
        P.outA = out; P.outB = out + (size_t)NA * 64;
        aggregate_n_k<<<(NA + NB) / 4, 256, 0, stream>>>(P);
    }
}